// Round 1
// baseline (5347.059 us; speedup 1.0000x reference)
//
#include <hip/hip_runtime.h>
#include <cstddef>

// ---------------- problem constants ----------------
// b=2, s=256, WIDTH=64, RANK=4, CLEVEL=1 (c=2), MLEVEL=2 (L=3), NB=4
// HID1=64, HID2=128

static constexpr int S_   = 256;
static constexpr int SC_  = 128;           // coarse grid (s/2)
static constexpr size_t NPIX = 2u * 256u * 256u;   // 131072 full-res pixels
static constexpr size_t NC   = 2u * 128u * 128u;   // 32768 coarse pixels

// ---------------- workspace layout (float offsets) ----------------
static constexpr size_t OFF_H      = 0;          // 2*256*256*64 = 8388608
static constexpr size_t OFF_X1     = 8388608;    // 8388608
static constexpr size_t OFF_YL1    = 16777216;   // 2*128*128*64 = 2097152
static constexpr size_t OFF_YL2    = 18874368;   // 2*64*64*64   = 524288
static constexpr size_t OFF_X2C    = 19398656;   // 2097152
static constexpr size_t OFF_YG     = 21495808;   // 512 (+pad to 1024)
static constexpr size_t OFF_HCHW   = 21496832;   // 8388608
static constexpr size_t OFF_HDT    = 29885440;   // 2*64*16384 = 2097152
static constexpr size_t OFF_CWT    = 31982592;   // 4*3*64*9*64 = 1327104
static constexpr size_t OFF_W3TPHI = 33309696;   // 4*256*128 = 131072
static constexpr size_t OFF_W3TPSI = 33440768;   // 131072
static constexpr size_t OFF_Q1T    = 33571840;   // 8192
// total = 33580032 floats = ~134.3 MB

// ---------------- helpers ----------------
__device__ inline float wave_sum64(float v) {
    v += __shfl_xor(v, 1);
    v += __shfl_xor(v, 2);
    v += __shfl_xor(v, 4);
    v += __shfl_xor(v, 8);
    v += __shfl_xor(v, 16);
    v += __shfl_xor(v, 32);
    return v;
}

struct Lerp { int i0, i1; float f; };
// jax.image.resize 'bilinear' upsample: src = (o+0.5)*Sin/Sout - 0.5, clamped lerp
__device__ inline Lerp lcoord(int o, float r, float off, int Sin) {
    float s = fmaxf(fmaf((float)o, r, off), 0.f);
    Lerp L;
    L.i0 = (int)s;
    L.f  = s - (float)L.i0;
    L.i1 = min(L.i0 + 1, Sin - 1);
    return L;
}
__device__ inline float bilerp64(const float* __restrict__ base, int Sin,
                                 const Lerp& ly, const Lerp& lx, int lane) {
    float v00 = base[((size_t)(ly.i0 * Sin + lx.i0)) * 64 + lane];
    float v01 = base[((size_t)(ly.i0 * Sin + lx.i1)) * 64 + lane];
    float v10 = base[((size_t)(ly.i1 * Sin + lx.i0)) * 64 + lane];
    float v11 = base[((size_t)(ly.i1 * Sin + lx.i1)) * 64 + lane];
    float a = v00 + lx.f * (v01 - v00);
    float b = v10 + lx.f * (v11 - v10);
    return a + ly.f * (b - a);
}

// ---------------- one-time weight transposes ----------------
// convW[i][l][oc][ic][3][3] -> cwt[i][l][ic][tap][oc]
__global__ __launch_bounds__(256) void k_transpose_convw(const float* __restrict__ w,
                                                         float* __restrict__ wt) {
    int idx = blockIdx.x * 256 + threadIdx.x;     // 4*3*64*9*64 = 1327104
    if (idx >= 4 * 3 * 64 * 64 * 9) return;
    int oc  = idx & 63;
    int tap = (idx >> 6) % 9;
    int ic  = (idx / (64 * 9)) & 63;
    int il  = idx / (64 * 9 * 64);
    wt[idx] = w[((size_t)(il * 64 + oc) * 64 + ic) * 9 + tap];
}
// W3[i][128][256] -> W3t[i][256][128]
__global__ __launch_bounds__(256) void k_transpose_w3(const float* __restrict__ w,
                                                      float* __restrict__ wt) {
    int idx = blockIdx.x * 256 + threadIdx.x;     // 4*256*128 = 131072
    if (idx >= 4 * 256 * 128) return;
    int k = idx & 127;
    int o = (idx >> 7) & 255;
    int i = idx >> 15;
    wt[idx] = w[(size_t)(i * 128 + k) * 256 + o];
}
// q1W[64][128] -> q1t[128][64]
__global__ __launch_bounds__(256) void k_transpose_q1(const float* __restrict__ w,
                                                      float* __restrict__ wt) {
    int idx = blockIdx.x * 256 + threadIdx.x;     // 8192
    if (idx >= 8192) return;
    int k = idx & 63;
    int j = idx >> 6;
    wt[idx] = w[k * 128 + j];
}

// ---------------- lift: h = [a0,a1,x] @ pW + pb (writes NHWC + CHW) ----------------
__global__ __launch_bounds__(256) void k_lift(const float* __restrict__ x,
                                              const float* __restrict__ a,
                                              const float* __restrict__ pW,
                                              const float* __restrict__ pb,
                                              float* __restrict__ h,
                                              float* __restrict__ hchw) {
    int p = blockIdx.x * 256 + threadIdx.x;       // 131072
    float a0 = a[(size_t)p * 2 + 0];
    float a1 = a[(size_t)p * 2 + 1];
    float xv = x[p];
    int b  = p >> 16;
    int yx = p & 65535;
    float vals[64];
#pragma unroll
    for (int c = 0; c < 64; ++c)
        vals[c] = fmaf(a0, pW[c], fmaf(a1, pW[64 + c], fmaf(xv, pW[128 + c], pb[c])));
    float* hp = h + (size_t)p * 64;
#pragma unroll
    for (int c = 0; c < 64; c += 4)
        *(float4*)(hp + c) = make_float4(vals[c], vals[c + 1], vals[c + 2], vals[c + 3]);
#pragma unroll
    for (int c = 0; c < 64; ++c)
        hchw[((size_t)(b * 64 + c)) * 65536 + yx] = vals[c];   // lanes: consecutive yx -> coalesced
}

// ---------------- conv 3x3 SAME (64->64) on (possibly strided) grid ----------------
// input: hchw full-res CHW; level pixel (oy,ox) maps to full-res (oy*st, ox*st)
__global__ __launch_bounds__(256) void k_conv(const float* __restrict__ hchw,
                                              const float* __restrict__ wt,   // [ic][tap][oc]
                                              const float* __restrict__ bias, // [oc]
                                              float* __restrict__ out,        // [b][Sl][Sl][64]
                                              int Sl, int st) {
    int p = blockIdx.x * 256 + threadIdx.x;
    int b = p / (Sl * Sl);
    int r = p - b * Sl * Sl;
    int oy = r / Sl;
    int ox = r - oy * Sl;

    int   off_[9];
    float msk_[9];
#pragma unroll
    for (int t = 0; t < 9; ++t) {
        int dy = t / 3 - 1, dx = t % 3 - 1;
        int ry = oy + dy, rx = ox + dx;
        bool ok = ((unsigned)ry < (unsigned)Sl) && ((unsigned)rx < (unsigned)Sl);
        off_[t] = ok ? (ry * st * 256 + rx * st) : 0;
        msk_[t] = ok ? 1.f : 0.f;
    }

    float acc[64];
#pragma unroll
    for (int oc = 0; oc < 64; ++oc) acc[oc] = bias[oc];

#pragma unroll 1
    for (int ic = 0; ic < 64; ++ic) {
        const float* base = hchw + (size_t)(b * 64 + ic) * 65536;
        float xv[9];
#pragma unroll
        for (int t = 0; t < 9; ++t) xv[t] = base[off_[t]] * msk_[t];
        const float* wr = wt + (size_t)ic * 576;   // 9*64
#pragma unroll
        for (int t = 0; t < 9; ++t) {
#pragma unroll
            for (int oc = 0; oc < 64; ++oc)
                acc[oc] = fmaf(xv[t], wr[t * 64 + oc], acc[oc]);
        }
    }

    float* op = out + (size_t)p * 64;
#pragma unroll
    for (int oc = 0; oc < 64; oc += 4)
        *(float4*)(op + oc) = make_float4(acc[oc], acc[oc + 1], acc[oc + 2], acc[oc + 3]);
}

// ---------------- downsample + transpose: hdt[b][w][n] = h[b][2cy][2cx][w] ----------------
__global__ __launch_bounds__(256) void k_hdt(const float* __restrict__ h,
                                             float* __restrict__ hdt) {
    __shared__ float lds[64 * 65];
    int t   = threadIdx.x;
    int blk = blockIdx.x;              // 512
    int b   = blk >> 8;
    int n0  = (blk & 255) * 64;
    int wv = t >> 6, lane = t & 63;
    for (int k = 0; k < 16; ++k) {
        int px = wv * 16 + k;
        int n  = n0 + px;
        int cy = n >> 7, cx = n & 127;
        float v = h[((size_t)((b * 256 + 2 * cy) * 256 + 2 * cx)) * 64 + lane];
        lds[px * 65 + lane] = v;
    }
    __syncthreads();
    int c = t >> 2, xi = (t & 3) * 16;
    for (int k = 0; k < 16; k += 4) {
        float4 o;
        o.x = lds[(xi + k + 0) * 65 + c];
        o.y = lds[(xi + k + 1) * 65 + c];
        o.z = lds[(xi + k + 2) * 65 + c];
        o.w = lds[(xi + k + 3) * 65 + c];
        *(float4*)(&hdt[((size_t)(b * 64 + c)) * 16384 + n0 + xi + k]) = o;
    }
}

// ---------------- lowrank pass A: psi MLP + y accumulation (atomics) ----------------
__global__ __launch_bounds__(256) void k_psi(const float* __restrict__ a,
                                             const float* __restrict__ x,
                                             const float* __restrict__ W1,
                                             const float* __restrict__ b1,
                                             const float* __restrict__ W2,
                                             const float* __restrict__ b2,
                                             const float* __restrict__ W3t,  // [256][128]
                                             const float* __restrict__ b3,
                                             const float* __restrict__ hdt,
                                             float* __restrict__ yg) {
    int p = blockIdx.x * 256 + threadIdx.x;   // 32768 coarse pixels
    int b = p >> 14, n = p & 16383;
    int cy = n >> 7, cx = n & 127;
    size_t apix = (size_t)((b * 256 + 2 * cy) * 256 + 2 * cx);
    float a0 = a[apix * 2], a1 = a[apix * 2 + 1], xv = x[apix];

    float h2[128];
#pragma unroll
    for (int j = 0; j < 128; ++j) h2[j] = b2[j];
#pragma unroll 1
    for (int k = 0; k < 64; ++k) {
        float h1 = fmaxf(fmaf(a0, W1[k], fmaf(a1, W1[64 + k], fmaf(xv, W1[128 + k], b1[k]))), 0.f);
        const float* wr = W2 + k * 128;
#pragma unroll
        for (int j = 0; j < 128; ++j) h2[j] = fmaf(h1, wr[j], h2[j]);
    }
#pragma unroll
    for (int j = 0; j < 128; ++j) h2[j] = fmaxf(h2[j], 0.f);

    int lane = threadIdx.x & 63;
    float v = 0.f;
#pragma unroll 1
    for (int o = 0; o < 256; ++o) {
        if ((o & 3) == 0) v = hdt[((size_t)(b * 64 + (o >> 2))) * 16384 + n];
        const float* wr = W3t + o * 128;
        float s0 = 0.f, s1 = 0.f, s2 = 0.f, s3 = 0.f;
#pragma unroll
        for (int k = 0; k < 128; k += 4) {
            s0 = fmaf(h2[k],     wr[k],     s0);
            s1 = fmaf(h2[k + 1], wr[k + 1], s1);
            s2 = fmaf(h2[k + 2], wr[k + 2], s2);
            s3 = fmaf(h2[k + 3], wr[k + 3], s3);
        }
        float s = ((s0 + s1) + (s2 + s3)) + b3[o];
        float part = wave_sum64(s * v);
        if (lane == 0) atomicAdd(&yg[b * 256 + o], part);
    }
}

// ---------------- lowrank pass B: phi MLP + x2c = phi . (y/n) ----------------
__global__ __launch_bounds__(256) void k_phi(const float* __restrict__ a,
                                             const float* __restrict__ x,
                                             const float* __restrict__ W1,
                                             const float* __restrict__ b1,
                                             const float* __restrict__ W2,
                                             const float* __restrict__ b2,
                                             const float* __restrict__ W3t,
                                             const float* __restrict__ b3,
                                             const float* __restrict__ yg,
                                             float* __restrict__ x2c) {
    int p = blockIdx.x * 256 + threadIdx.x;
    int b = p >> 14, n = p & 16383;
    int cy = n >> 7, cx = n & 127;
    size_t apix = (size_t)((b * 256 + 2 * cy) * 256 + 2 * cx);
    float a0 = a[apix * 2], a1 = a[apix * 2 + 1], xv = x[apix];

    float h2[128];
#pragma unroll
    for (int j = 0; j < 128; ++j) h2[j] = b2[j];
#pragma unroll 1
    for (int k = 0; k < 64; ++k) {
        float h1 = fmaxf(fmaf(a0, W1[k], fmaf(a1, W1[64 + k], fmaf(xv, W1[128 + k], b1[k]))), 0.f);
        const float* wr = W2 + k * 128;
#pragma unroll
        for (int j = 0; j < 128; ++j) h2[j] = fmaf(h1, wr[j], h2[j]);
    }
#pragma unroll
    for (int j = 0; j < 128; ++j) h2[j] = fmaxf(h2[j], 0.f);

    const float inv_n = 1.f / 16384.f;
    float outw = 0.f;
#pragma unroll 1
    for (int o = 0; o < 256; ++o) {
        const float* wr = W3t + o * 128;
        float s0 = 0.f, s1 = 0.f, s2 = 0.f, s3 = 0.f;
#pragma unroll
        for (int k = 0; k < 128; k += 4) {
            s0 = fmaf(h2[k],     wr[k],     s0);
            s1 = fmaf(h2[k + 1], wr[k + 1], s1);
            s2 = fmaf(h2[k + 2], wr[k + 2], s2);
            s3 = fmaf(h2[k + 3], wr[k + 3], s3);
        }
        float s = ((s0 + s1) + (s2 + s3)) + b3[o];
        outw = fmaf(s, yg[b * 256 + o] * inv_n, outw);
        if ((o & 3) == 3) {
            x2c[(size_t)p * 64 + (o >> 2)] = outw;
            outw = 0.f;
        }
    }
}

// ---------------- epilogue: h = LN(x1 + up(yl1) + up(yl2) + up(x2c)); relu opt ----------------
__global__ __launch_bounds__(256) void k_epilogue(const float* __restrict__ x1,
                                                  const float* __restrict__ yl1,
                                                  const float* __restrict__ yl2,
                                                  const float* __restrict__ x2c,
                                                  const float* __restrict__ lnG,
                                                  const float* __restrict__ lnB,
                                                  float* __restrict__ h,
                                                  float* __restrict__ hchw,
                                                  int do_relu) {
    __shared__ float lds[64 * 17];
    int t    = threadIdx.x;
    int blk  = blockIdx.x;                 // 8192 = 2 * 256 * 16
    int b    = blk >> 12;
    int rest = blk & 4095;
    int y    = rest >> 4;
    int x0   = (rest & 15) << 4;
    int wv = t >> 6, lane = t & 63;

    float g = lnG[lane], be = lnB[lane];
    const float* Y1 = yl1 + (size_t)b * 16384 * 64;
    const float* Y2 = yl2 + (size_t)b * 4096 * 64;
    const float* XC = x2c + (size_t)b * 16384 * 64;

    for (int pp = 0; pp < 4; ++pp) {
        int xl = wv * 4 + pp;
        int xx = x0 + xl;
        size_t pix = (size_t)((b * 256 + y) * 256 + xx);
        float v = x1[pix * 64 + lane];
        {   // yl1: 128 -> 256 (scale 2)
            Lerp ly = lcoord(y, 0.5f, -0.25f, 128);
            Lerp lx = lcoord(xx, 0.5f, -0.25f, 128);
            v += bilerp64(Y1, 128, ly, lx, lane);
        }
        {   // yl2: 64 -> 256 (scale 4)
            Lerp ly = lcoord(y, 0.25f, -0.375f, 64);
            Lerp lx = lcoord(xx, 0.25f, -0.375f, 64);
            v += bilerp64(Y2, 64, ly, lx, lane);
        }
        {   // x2c: 128 -> 256 (scale 2)
            Lerp ly = lcoord(y, 0.5f, -0.25f, 128);
            Lerp lx = lcoord(xx, 0.5f, -0.25f, 128);
            v += bilerp64(XC, 128, ly, lx, lane);
        }
        // LayerNorm over 64 channels
        float mu  = wave_sum64(v) * (1.f / 64.f);
        float d   = v - mu;
        float var = wave_sum64(d * d) * (1.f / 64.f);
        float ov  = fmaf(d * rsqrtf(var + 1e-5f), g, be);
        if (do_relu) ov = fmaxf(ov, 0.f);
        h[pix * 64 + lane] = ov;
        lds[lane * 17 + xl] = ov;
    }
    __syncthreads();
    // transpose -> CHW, full 64B lines per 4 lanes
    int c = t >> 2, xi = (t & 3) << 2;
    float4 o4 = make_float4(lds[c * 17 + xi], lds[c * 17 + xi + 1],
                            lds[c * 17 + xi + 2], lds[c * 17 + xi + 3]);
    *(float4*)(&hchw[((size_t)(b * 64 + c)) * 65536 + (size_t)y * 256 + x0 + xi]) = o4;
}

// ---------------- head: out = relu(h@q1W+q1b) @ q2W + q2b ----------------
__global__ __launch_bounds__(256) void k_head(const float* __restrict__ h,
                                              const float* __restrict__ q1t, // [128][64]
                                              const float* __restrict__ q1b,
                                              const float* __restrict__ q2,  // [128]
                                              const float* __restrict__ q2b,
                                              float* __restrict__ out) {
    int p = blockIdx.x * 256 + threadIdx.x;   // 131072
    float hv[64];
    const float* hp = h + (size_t)p * 64;
#pragma unroll
    for (int w = 0; w < 64; w += 4) {
        float4 t4 = *(const float4*)(hp + w);
        hv[w] = t4.x; hv[w + 1] = t4.y; hv[w + 2] = t4.z; hv[w + 3] = t4.w;
    }
    float o = q2b[0];
#pragma unroll 1
    for (int j = 0; j < 128; ++j) {
        const float* r = q1t + j * 64;
        float s0 = 0.f, s1 = 0.f, s2 = 0.f, s3 = 0.f;
#pragma unroll
        for (int w = 0; w < 64; w += 4) {
            s0 = fmaf(hv[w],     r[w],     s0);
            s1 = fmaf(hv[w + 1], r[w + 1], s1);
            s2 = fmaf(hv[w + 2], r[w + 2], s2);
            s3 = fmaf(hv[w + 3], r[w + 3], s3);
        }
        float s = ((s0 + s1) + (s2 + s3)) + q1b[j];
        o = fmaf(fmaxf(s, 0.f), q2[j], o);
    }
    out[p] = o;
}

// ---------------- launch ----------------
extern "C" void kernel_launch(void* const* d_in, const int* in_sizes, int n_in,
                              void* d_out, int out_size, void* d_ws, size_t ws_size,
                              hipStream_t stream) {
    const float* x     = (const float*)d_in[0];
    const float* a     = (const float*)d_in[1];
    const float* pW    = (const float*)d_in[2];
    const float* pb    = (const float*)d_in[3];
    const float* q1W   = (const float*)d_in[4];
    const float* q1b   = (const float*)d_in[5];
    const float* q2W   = (const float*)d_in[6];
    const float* q2b   = (const float*)d_in[7];
    const float* phiW1 = (const float*)d_in[8];
    const float* phib1 = (const float*)d_in[9];
    const float* phiW2 = (const float*)d_in[10];
    const float* phib2 = (const float*)d_in[11];
    const float* phiW3 = (const float*)d_in[12];
    const float* phib3 = (const float*)d_in[13];
    const float* psiW1 = (const float*)d_in[14];
    const float* psib1 = (const float*)d_in[15];
    const float* psiW2 = (const float*)d_in[16];
    const float* psib2 = (const float*)d_in[17];
    const float* psiW3 = (const float*)d_in[18];
    const float* psib3 = (const float*)d_in[19];
    const float* lnG   = (const float*)d_in[20];
    const float* lnB   = (const float*)d_in[21];
    const float* convW = (const float*)d_in[22];
    const float* convb = (const float*)d_in[23];

    float* ws   = (float*)d_ws;
    float* h    = ws + OFF_H;
    float* x1   = ws + OFF_X1;
    float* yl1  = ws + OFF_YL1;
    float* yl2  = ws + OFF_YL2;
    float* x2c  = ws + OFF_X2C;
    float* yg   = ws + OFF_YG;
    float* hchw = ws + OFF_HCHW;
    float* hdt  = ws + OFF_HDT;
    float* cwt  = ws + OFF_CWT;
    float* w3tphi = ws + OFF_W3TPHI;
    float* w3tpsi = ws + OFF_W3TPSI;
    float* q1t  = ws + OFF_Q1T;

    // one-time weight transforms (cheap; run every call for determinism)
    k_transpose_convw<<<5184, 256, 0, stream>>>(convW, cwt);
    k_transpose_w3<<<512, 256, 0, stream>>>(phiW3, w3tphi);
    k_transpose_w3<<<512, 256, 0, stream>>>(psiW3, w3tpsi);
    k_transpose_q1<<<32, 256, 0, stream>>>(q1W, q1t);

    k_lift<<<512, 256, 0, stream>>>(x, a, pW, pb, h, hchw);

    for (int i = 0; i < 4; ++i) {
        k_conv<<<512, 256, 0, stream>>>(hchw, cwt + (size_t)(i * 3 + 0) * 36864,
                                        convb + (i * 3 + 0) * 64, x1, 256, 1);
        k_conv<<<128, 256, 0, stream>>>(hchw, cwt + (size_t)(i * 3 + 1) * 36864,
                                        convb + (i * 3 + 1) * 64, yl1, 128, 2);
        k_conv<<<32, 256, 0, stream>>>(hchw, cwt + (size_t)(i * 3 + 2) * 36864,
                                       convb + (i * 3 + 2) * 64, yl2, 64, 4);
        k_hdt<<<512, 256, 0, stream>>>(h, hdt);
        hipMemsetAsync(yg, 0, 512 * sizeof(float), stream);
        k_psi<<<128, 256, 0, stream>>>(a, x,
                                       psiW1 + i * 192, psib1 + i * 64,
                                       psiW2 + i * 8192, psib2 + i * 128,
                                       w3tpsi + (size_t)i * 32768, psib3 + i * 256,
                                       hdt, yg);
        k_phi<<<128, 256, 0, stream>>>(a, x,
                                       phiW1 + i * 192, phib1 + i * 64,
                                       phiW2 + i * 8192, phib2 + i * 128,
                                       w3tphi + (size_t)i * 32768, phib3 + i * 256,
                                       yg, x2c);
        k_epilogue<<<8192, 256, 0, stream>>>(x1, yl1, yl2, x2c,
                                             lnG + i * 64, lnB + i * 64,
                                             h, hchw, (i < 3) ? 1 : 0);
    }

    k_head<<<512, 256, 0, stream>>>(h, q1t, q1b, q2W, q2b, (float*)d_out);
}

// Round 2
// 2513.896 us; speedup vs baseline: 2.1270x; 2.1270x over previous
//
#include <hip/hip_runtime.h>
#include <cstddef>

// ---------------- problem constants ----------------
// b=2, s=256, WIDTH=64, RANK=4, CLEVEL=1 (c=2), MLEVEL=2 (L=3), NB=4
// HID1=64, HID2=128

// ---------------- workspace layout (float offsets) ----------------
static constexpr size_t OFF_H      = 0;          // 2*256*256*64 = 8388608
static constexpr size_t OFF_X1     = 8388608;    // 8388608
static constexpr size_t OFF_YL1    = 16777216;   // 2*128*128*64 = 2097152
static constexpr size_t OFF_YL2    = 18874368;   // 2*64*64*64   = 524288
static constexpr size_t OFF_X2C    = 19398656;   // 2097152
static constexpr size_t OFF_HCHW   = 21495808;   // 8388608  (H2psi/H2phi overlay here)
static constexpr size_t OFF_CWT    = 29884416;   // 4*3*64*9*64 = 1327104
static constexpr size_t OFF_Q1T    = 31211520;   // 8192
static constexpr size_t OFF_G      = 31219712;   // 2*64*128 = 16384
static constexpr size_t OFF_SV     = 31236096;   // 128
static constexpr size_t OFF_C      = 31236224;   // 2*64*128 = 16384
static constexpr size_t OFF_D      = 31252608;   // 128
// end = 31252736 floats = ~125 MB (round 1 proved >=134 MB available)

// H2psi/H2phi overlay hchw: hchw is dead between "convs of iter i read it"
// and "epilogue of iter i rewrites it"; all lowrank kernels run in between
// (stream-ordered). 2*(32768*128) = 8388608 floats = exact size match.

// ---------------- helpers ----------------
__device__ inline float wave_sum64(float v) {
    v += __shfl_xor(v, 1);
    v += __shfl_xor(v, 2);
    v += __shfl_xor(v, 4);
    v += __shfl_xor(v, 8);
    v += __shfl_xor(v, 16);
    v += __shfl_xor(v, 32);
    return v;
}

// full-res flat pixel index of coarse pixel (b, n): n in [0,16384)
__device__ inline size_t fullpix(int b, int n) {
    return (size_t)(b * 65536 + (n >> 7) * 512 + ((n & 127) << 1));
}

struct Lerp { int i0, i1; float f; };
// jax.image.resize 'bilinear' upsample: src = (o+0.5)*Sin/Sout - 0.5, clamped lerp
__device__ inline Lerp lcoord(int o, float r, float off, int Sin) {
    float s = fmaxf(fmaf((float)o, r, off), 0.f);
    Lerp L;
    L.i0 = (int)s;
    L.f  = s - (float)L.i0;
    L.i1 = min(L.i0 + 1, Sin - 1);
    return L;
}
__device__ inline float bilerp64(const float* __restrict__ base, int Sin,
                                 const Lerp& ly, const Lerp& lx, int lane) {
    float v00 = base[((size_t)(ly.i0 * Sin + lx.i0)) * 64 + lane];
    float v01 = base[((size_t)(ly.i0 * Sin + lx.i1)) * 64 + lane];
    float v10 = base[((size_t)(ly.i1 * Sin + lx.i0)) * 64 + lane];
    float v11 = base[((size_t)(ly.i1 * Sin + lx.i1)) * 64 + lane];
    float a = v00 + lx.f * (v01 - v00);
    float b = v10 + lx.f * (v11 - v10);
    return a + ly.f * (b - a);
}

// ---------------- one-time weight transposes ----------------
// convW[i][l][oc][ic][3][3] -> cwt[i][l][ic][tap][oc]
__global__ __launch_bounds__(256) void k_transpose_convw(const float* __restrict__ w,
                                                         float* __restrict__ wt) {
    int idx = blockIdx.x * 256 + threadIdx.x;     // 4*3*64*9*64 = 1327104
    if (idx >= 4 * 3 * 64 * 64 * 9) return;
    int oc  = idx & 63;
    int tap = (idx >> 6) % 9;
    int ic  = (idx / (64 * 9)) & 63;
    int il  = idx / (64 * 9 * 64);
    wt[idx] = w[((size_t)(il * 64 + oc) * 64 + ic) * 9 + tap];
}
// q1W[64][128] -> q1t[128][64]
__global__ __launch_bounds__(256) void k_transpose_q1(const float* __restrict__ w,
                                                      float* __restrict__ wt) {
    int idx = blockIdx.x * 256 + threadIdx.x;     // 8192
    if (idx >= 8192) return;
    int k = idx & 63;
    int j = idx >> 6;
    wt[idx] = w[k * 128 + j];
}

// ---------------- lift: h = [a0,a1,x] @ pW + pb (writes NHWC + CHW) ----------------
__global__ __launch_bounds__(256) void k_lift(const float* __restrict__ x,
                                              const float* __restrict__ a,
                                              const float* __restrict__ pW,
                                              const float* __restrict__ pb,
                                              float* __restrict__ h,
                                              float* __restrict__ hchw) {
    int p = blockIdx.x * 256 + threadIdx.x;       // 131072
    float a0 = a[(size_t)p * 2 + 0];
    float a1 = a[(size_t)p * 2 + 1];
    float xv = x[p];
    int b  = p >> 16;
    int yx = p & 65535;
    float vals[64];
#pragma unroll
    for (int c = 0; c < 64; ++c)
        vals[c] = fmaf(a0, pW[c], fmaf(a1, pW[64 + c], fmaf(xv, pW[128 + c], pb[c])));
    float* hp = h + (size_t)p * 64;
#pragma unroll
    for (int c = 0; c < 64; c += 4)
        *(float4*)(hp + c) = make_float4(vals[c], vals[c + 1], vals[c + 2], vals[c + 3]);
#pragma unroll
    for (int c = 0; c < 64; ++c)
        hchw[((size_t)(b * 64 + c)) * 65536 + yx] = vals[c];
}

// ---------------- conv 3x3 SAME (64->64) on (possibly strided) grid ----------------
__global__ __launch_bounds__(256) void k_conv(const float* __restrict__ hchw,
                                              const float* __restrict__ wt,   // [ic][tap][oc]
                                              const float* __restrict__ bias, // [oc]
                                              float* __restrict__ out,        // [b][Sl][Sl][64]
                                              int Sl, int st) {
    int p = blockIdx.x * 256 + threadIdx.x;
    int b = p / (Sl * Sl);
    int r = p - b * Sl * Sl;
    int oy = r / Sl;
    int ox = r - oy * Sl;

    int   off_[9];
    float msk_[9];
#pragma unroll
    for (int t = 0; t < 9; ++t) {
        int dy = t / 3 - 1, dx = t % 3 - 1;
        int ry = oy + dy, rx = ox + dx;
        bool ok = ((unsigned)ry < (unsigned)Sl) && ((unsigned)rx < (unsigned)Sl);
        off_[t] = ok ? (ry * st * 256 + rx * st) : 0;
        msk_[t] = ok ? 1.f : 0.f;
    }

    float acc[64];
#pragma unroll
    for (int oc = 0; oc < 64; ++oc) acc[oc] = bias[oc];

#pragma unroll 1
    for (int ic = 0; ic < 64; ++ic) {
        const float* base = hchw + (size_t)(b * 64 + ic) * 65536;
        float xv[9];
#pragma unroll
        for (int t = 0; t < 9; ++t) xv[t] = base[off_[t]] * msk_[t];
        const float* wr = wt + (size_t)ic * 576;   // 9*64
#pragma unroll
        for (int t = 0; t < 9; ++t) {
#pragma unroll
            for (int oc = 0; oc < 64; ++oc)
                acc[oc] = fmaf(xv[t], wr[t * 64 + oc], acc[oc]);
        }
    }

    float* op = out + (size_t)p * 64;
#pragma unroll
    for (int oc = 0; oc < 64; oc += 4)
        *(float4*)(op + oc) = make_float4(acc[oc], acc[oc + 1], acc[oc + 2], acc[oc + 3]);
}

// ---------------- mlp12: H2 = relu(relu(a@W1+b1)@W2+b2) for psi AND phi ----------------
// grid 512: blk>>8 selects mlp (0=psi,1=phi). 2 threads per pixel (64 h2-outputs each).
__global__ __launch_bounds__(256) void k_mlp12(
    const float* __restrict__ a, const float* __restrict__ x,
    const float* __restrict__ W1a, const float* __restrict__ b1a,
    const float* __restrict__ W2a, const float* __restrict__ b2a,
    const float* __restrict__ W1b, const float* __restrict__ b1b,
    const float* __restrict__ W2b, const float* __restrict__ b2b,
    float* __restrict__ H2a, float* __restrict__ H2b) {
    int blk = blockIdx.x;
    int m = blk >> 8;
    int t = threadIdx.x;
    int pxl = ((blk & 255) << 7) | (t & 127);      // 0..32767
    int j0 = __builtin_amdgcn_readfirstlane((t >> 7) << 6);  // wave-uniform half
    const float* W1 = m ? W1b : W1a;
    const float* b1 = m ? b1b : b1a;
    const float* W2 = m ? W2b : W2a;
    const float* b2 = m ? b2b : b2a;
    float* H2 = m ? H2b : H2a;
    int b = pxl >> 14, n = pxl & 16383;
    size_t apix = fullpix(b, n);
    float a0 = a[apix * 2], a1 = a[apix * 2 + 1], xv = x[apix];

    float acc[64];
#pragma unroll
    for (int j = 0; j < 64; ++j) acc[j] = b2[j0 + j];
#pragma unroll 1
    for (int k = 0; k < 64; ++k) {
        float h1 = fmaxf(fmaf(a0, W1[k], fmaf(a1, W1[64 + k], fmaf(xv, W1[128 + k], b1[k]))), 0.f);
        const float* wr = W2 + k * 128 + j0;
#pragma unroll
        for (int j = 0; j < 64; ++j) acc[j] = fmaf(h1, wr[j], acc[j]);
    }
    float* op = H2 + (size_t)pxl * 128 + j0;
#pragma unroll
    for (int j = 0; j < 64; j += 4)
        *(float4*)(op + j) = make_float4(fmaxf(acc[j], 0.f), fmaxf(acc[j + 1], 0.f),
                                         fmaxf(acc[j + 2], 0.f), fmaxf(acc[j + 3], 0.f));
}

// ---------------- G[b][w][k] = sum_n v[n][w] * H2psi[n][k] (outer-product GEMM) ----------------
__global__ __launch_bounds__(256) void k_g(const float* __restrict__ h,
                                           const float* __restrict__ H2psi,
                                           float* __restrict__ G) {
    __shared__ float vt[16][64];
    __shared__ float h2t[16][128];
    int blk = blockIdx.x;            // 128: 64 per b
    int b = blk >> 6;
    int n0 = (blk & 63) << 8;        // 256 px per block
    int t = threadIdx.x;
    int wt = (t >> 5) << 3;          // 0..56
    int kt = (t & 31) << 2;          // 0..124
    float acc[8][4];
#pragma unroll
    for (int i = 0; i < 8; ++i)
#pragma unroll
        for (int j = 0; j < 4; ++j) acc[i][j] = 0.f;

    int pl = t >> 4;
    int w4 = (t & 15) << 2;
    int k8 = (t & 15) << 3;
    for (int c16 = 0; c16 < 16; ++c16) {
        int n = n0 + (c16 << 4) + pl;
        *(float4*)&vt[pl][w4] = *(const float4*)&h[fullpix(b, n) * 64 + w4];
        const float* hp = &H2psi[((size_t)(b * 16384 + n)) * 128 + k8];
        *(float4*)&h2t[pl][k8]     = *(const float4*)hp;
        *(float4*)&h2t[pl][k8 + 4] = *(const float4*)(hp + 4);
        __syncthreads();
#pragma unroll 4
        for (int nn = 0; nn < 16; ++nn) {
            float4 hv = *(float4*)&h2t[nn][kt];
            float4 v0 = *(float4*)&vt[nn][wt];
            float4 v1 = *(float4*)&vt[nn][wt + 4];
            float vv[8] = {v0.x, v0.y, v0.z, v0.w, v1.x, v1.y, v1.z, v1.w};
            float hh[4] = {hv.x, hv.y, hv.z, hv.w};
#pragma unroll
            for (int i = 0; i < 8; ++i)
#pragma unroll
                for (int j = 0; j < 4; ++j) acc[i][j] = fmaf(vv[i], hh[j], acc[i][j]);
        }
        __syncthreads();
    }
#pragma unroll
    for (int i = 0; i < 8; ++i)
#pragma unroll
        for (int j = 0; j < 4; ++j)
            atomicAdd(&G[((size_t)(b * 64 + wt + i)) * 128 + kt + j], acc[i][j]);
}

// ---------------- sv[b][w] = sum_n v[n][w] ----------------
__global__ __launch_bounds__(256) void k_sv(const float* __restrict__ h,
                                            float* __restrict__ sv) {
    __shared__ float red[4][64];
    int blk = blockIdx.x;            // 64: 32 per b
    int b = blk >> 5;
    int n0 = (blk & 31) << 9;        // 512 px
    int t = threadIdx.x;
    int w = t & 63, g = t >> 6;
    float s = 0.f;
    for (int q = 0; q < 128; ++q) {
        int n = n0 + (g << 7) + q;
        s += h[fullpix(b, n) * 64 + w];
    }
    red[g][w] = s;
    __syncthreads();
    if (t < 64) atomicAdd(&sv[b * 64 + t], red[0][t] + red[1][t] + red[2][t] + red[3][t]);
}

// ---------------- finalize: ybar -> c[b][w][k], d[b][w] ----------------
// y[b][o] = sum_k W3psi[k][o]*G[b][o>>2][k] + b3psi[o]*sv[b][o>>2]; ybar = y/16384
// c[b][w][k] = sum_r W3phi[k][w4+r]*ybar[w4+r]; d[b][w] = sum_r b3phi[w4+r]*ybar[w4+r]
__global__ __launch_bounds__(256) void k_yc(const float* __restrict__ G,
                                            const float* __restrict__ sv,
                                            const float* __restrict__ W3psi,
                                            const float* __restrict__ b3psi,
                                            const float* __restrict__ W3phi,
                                            const float* __restrict__ b3phi,
                                            float* __restrict__ C,
                                            float* __restrict__ D) {
    __shared__ float ybar[256];
    int b = blockIdx.x;              // 2
    int t = threadIdx.x;
    {
        int o = t, w = o >> 2;
        float s = b3psi[o] * sv[b * 64 + w];
        const float* gp = &G[(size_t)(b * 64 + w) * 128];
#pragma unroll 4
        for (int k = 0; k < 128; ++k) s = fmaf(W3psi[k * 256 + o], gp[k], s);
        ybar[o] = s * (1.f / 16384.f);
    }
    __syncthreads();
    for (int rep = 0; rep < 32; ++rep) {
        int e = rep * 256 + t;       // 8192
        int w = e >> 7, k = e & 127;
        const float* wp = &W3phi[k * 256 + w * 4];
        C[b * 8192 + e] = fmaf(wp[0], ybar[w * 4],
                          fmaf(wp[1], ybar[w * 4 + 1],
                          fmaf(wp[2], ybar[w * 4 + 2], wp[3] * ybar[w * 4 + 3])));
    }
    if (t < 64) {
        int w = t;
        D[b * 64 + w] = b3phi[w * 4] * ybar[w * 4] + b3phi[w * 4 + 1] * ybar[w * 4 + 1]
                      + b3phi[w * 4 + 2] * ybar[w * 4 + 2] + b3phi[w * 4 + 3] * ybar[w * 4 + 3];
    }
}

// ---------------- x2c[px][w] = H2phi[px][:] . c[b][w][:] + d[b][w] ----------------
__global__ __launch_bounds__(256) void k_x2c(const float* __restrict__ H2phi,
                                             const float* __restrict__ C,
                                             const float* __restrict__ D,
                                             float* __restrict__ x2c) {
    __shared__ float cl[8192];       // c[b]: 64 w x 128 k
    int blk = blockIdx.x;            // 128
    int b = blk >> 6;
    int px0 = blk << 8;              // 256 px per block
    int t = threadIdx.x;
    const float* cp = C + b * 8192;
#pragma unroll
    for (int rep = 0; rep < 8; ++rep) {
        int f = rep * 1024 + t * 4;
        *(float4*)&cl[f] = *(const float4*)&cp[f];
    }
    __syncthreads();

    int w0 = __builtin_amdgcn_readfirstlane((t >> 6) << 4);  // wave-uniform 0/16/32/48
    int px = px0 + ((t & 63) << 2);
    float acc[4][16];
#pragma unroll
    for (int i = 0; i < 4; ++i)
#pragma unroll
        for (int j = 0; j < 16; ++j) acc[i][j] = 0.f;

    const float* hbase = H2phi + (size_t)px * 128;
#pragma unroll 2
    for (int kq = 0; kq < 32; ++kq) {
        float4 h2q[4];
#pragma unroll
        for (int i = 0; i < 4; ++i) h2q[i] = *(const float4*)&hbase[i * 128 + kq * 4];
#pragma unroll
        for (int j = 0; j < 16; ++j) {
            float4 cq = *(float4*)&cl[(w0 + j) * 128 + kq * 4];
#pragma unroll
            for (int i = 0; i < 4; ++i) {
                acc[i][j] = fmaf(h2q[i].x, cq.x, acc[i][j]);
                acc[i][j] = fmaf(h2q[i].y, cq.y, acc[i][j]);
                acc[i][j] = fmaf(h2q[i].z, cq.z, acc[i][j]);
                acc[i][j] = fmaf(h2q[i].w, cq.w, acc[i][j]);
            }
        }
    }
#pragma unroll
    for (int i = 0; i < 4; ++i) {
        float* op = &x2c[(size_t)(px + i) * 64 + w0];
#pragma unroll
        for (int j = 0; j < 16; j += 4) {
            float4 o4 = make_float4(acc[i][j]     + D[b * 64 + w0 + j],
                                    acc[i][j + 1] + D[b * 64 + w0 + j + 1],
                                    acc[i][j + 2] + D[b * 64 + w0 + j + 2],
                                    acc[i][j + 3] + D[b * 64 + w0 + j + 3]);
            *(float4*)(op + j) = o4;
        }
    }
}

// ---------------- epilogue: h = LN(x1 + up(yl1) + up(yl2) + up(x2c)); relu opt ----------------
__global__ __launch_bounds__(256) void k_epilogue(const float* __restrict__ x1,
                                                  const float* __restrict__ yl1,
                                                  const float* __restrict__ yl2,
                                                  const float* __restrict__ x2c,
                                                  const float* __restrict__ lnG,
                                                  const float* __restrict__ lnB,
                                                  float* __restrict__ h,
                                                  float* __restrict__ hchw,
                                                  int do_relu) {
    __shared__ float lds[64 * 17];
    int t    = threadIdx.x;
    int blk  = blockIdx.x;                 // 8192 = 2 * 256 * 16
    int b    = blk >> 12;
    int rest = blk & 4095;
    int y    = rest >> 4;
    int x0   = (rest & 15) << 4;
    int wv = t >> 6, lane = t & 63;

    float g = lnG[lane], be = lnB[lane];
    const float* Y1 = yl1 + (size_t)b * 16384 * 64;
    const float* Y2 = yl2 + (size_t)b * 4096 * 64;
    const float* XC = x2c + (size_t)b * 16384 * 64;

    for (int pp = 0; pp < 4; ++pp) {
        int xl = wv * 4 + pp;
        int xx = x0 + xl;
        size_t pix = (size_t)((b * 256 + y) * 256 + xx);
        float v = x1[pix * 64 + lane];
        {   // yl1: 128 -> 256 (scale 2)
            Lerp ly = lcoord(y, 0.5f, -0.25f, 128);
            Lerp lx = lcoord(xx, 0.5f, -0.25f, 128);
            v += bilerp64(Y1, 128, ly, lx, lane);
        }
        {   // yl2: 64 -> 256 (scale 4)
            Lerp ly = lcoord(y, 0.25f, -0.375f, 64);
            Lerp lx = lcoord(xx, 0.25f, -0.375f, 64);
            v += bilerp64(Y2, 64, ly, lx, lane);
        }
        {   // x2c: 128 -> 256 (scale 2)
            Lerp ly = lcoord(y, 0.5f, -0.25f, 128);
            Lerp lx = lcoord(xx, 0.5f, -0.25f, 128);
            v += bilerp64(XC, 128, ly, lx, lane);
        }
        float mu  = wave_sum64(v) * (1.f / 64.f);
        float d   = v - mu;
        float var = wave_sum64(d * d) * (1.f / 64.f);
        float ov  = fmaf(d * rsqrtf(var + 1e-5f), g, be);
        if (do_relu) ov = fmaxf(ov, 0.f);
        h[pix * 64 + lane] = ov;
        lds[lane * 17 + xl] = ov;
    }
    __syncthreads();
    int c = t >> 2, xi = (t & 3) << 2;
    float4 o4 = make_float4(lds[c * 17 + xi], lds[c * 17 + xi + 1],
                            lds[c * 17 + xi + 2], lds[c * 17 + xi + 3]);
    *(float4*)(&hchw[((size_t)(b * 64 + c)) * 65536 + (size_t)y * 256 + x0 + xi]) = o4;
}

// ---------------- head: out = relu(h@q1W+q1b) @ q2W + q2b ----------------
__global__ __launch_bounds__(256) void k_head(const float* __restrict__ h,
                                              const float* __restrict__ q1t, // [128][64]
                                              const float* __restrict__ q1b,
                                              const float* __restrict__ q2,  // [128]
                                              const float* __restrict__ q2b,
                                              float* __restrict__ out) {
    int p = blockIdx.x * 256 + threadIdx.x;   // 131072
    float hv[64];
    const float* hp = h + (size_t)p * 64;
#pragma unroll
    for (int w = 0; w < 64; w += 4) {
        float4 t4 = *(const float4*)(hp + w);
        hv[w] = t4.x; hv[w + 1] = t4.y; hv[w + 2] = t4.z; hv[w + 3] = t4.w;
    }
    float o = q2b[0];
#pragma unroll 1
    for (int j = 0; j < 128; ++j) {
        const float* r = q1t + j * 64;
        float s0 = 0.f, s1 = 0.f, s2 = 0.f, s3 = 0.f;
#pragma unroll
        for (int w = 0; w < 64; w += 4) {
            s0 = fmaf(hv[w],     r[w],     s0);
            s1 = fmaf(hv[w + 1], r[w + 1], s1);
            s2 = fmaf(hv[w + 2], r[w + 2], s2);
            s3 = fmaf(hv[w + 3], r[w + 3], s3);
        }
        float s = ((s0 + s1) + (s2 + s3)) + q1b[j];
        o = fmaf(fmaxf(s, 0.f), q2[j], o);
    }
    out[p] = o;
}

// ---------------- launch ----------------
extern "C" void kernel_launch(void* const* d_in, const int* in_sizes, int n_in,
                              void* d_out, int out_size, void* d_ws, size_t ws_size,
                              hipStream_t stream) {
    const float* x     = (const float*)d_in[0];
    const float* a     = (const float*)d_in[1];
    const float* pW    = (const float*)d_in[2];
    const float* pb    = (const float*)d_in[3];
    const float* q1W   = (const float*)d_in[4];
    const float* q1b   = (const float*)d_in[5];
    const float* q2W   = (const float*)d_in[6];
    const float* q2b   = (const float*)d_in[7];
    const float* phiW1 = (const float*)d_in[8];
    const float* phib1 = (const float*)d_in[9];
    const float* phiW2 = (const float*)d_in[10];
    const float* phib2 = (const float*)d_in[11];
    const float* phiW3 = (const float*)d_in[12];
    const float* phib3 = (const float*)d_in[13];
    const float* psiW1 = (const float*)d_in[14];
    const float* psib1 = (const float*)d_in[15];
    const float* psiW2 = (const float*)d_in[16];
    const float* psib2 = (const float*)d_in[17];
    const float* psiW3 = (const float*)d_in[18];
    const float* psib3 = (const float*)d_in[19];
    const float* lnG   = (const float*)d_in[20];
    const float* lnB   = (const float*)d_in[21];
    const float* convW = (const float*)d_in[22];
    const float* convb = (const float*)d_in[23];

    float* ws    = (float*)d_ws;
    float* h     = ws + OFF_H;
    float* x1    = ws + OFF_X1;
    float* yl1   = ws + OFF_YL1;
    float* yl2   = ws + OFF_YL2;
    float* x2c   = ws + OFF_X2C;
    float* hchw  = ws + OFF_HCHW;
    float* H2psi = ws + OFF_HCHW;             // overlay (see note at top)
    float* H2phi = ws + OFF_HCHW + 4194304;
    float* cwt   = ws + OFF_CWT;
    float* q1t   = ws + OFF_Q1T;
    float* G     = ws + OFF_G;
    float* sv    = ws + OFF_SV;
    float* C     = ws + OFF_C;
    float* D     = ws + OFF_D;

    k_transpose_convw<<<5184, 256, 0, stream>>>(convW, cwt);
    k_transpose_q1<<<32, 256, 0, stream>>>(q1W, q1t);

    k_lift<<<512, 256, 0, stream>>>(x, a, pW, pb, h, hchw);

    for (int i = 0; i < 4; ++i) {
        k_conv<<<512, 256, 0, stream>>>(hchw, cwt + (size_t)(i * 3 + 0) * 36864,
                                        convb + (i * 3 + 0) * 64, x1, 256, 1);
        k_conv<<<128, 256, 0, stream>>>(hchw, cwt + (size_t)(i * 3 + 1) * 36864,
                                        convb + (i * 3 + 1) * 64, yl1, 128, 2);
        k_conv<<<32, 256, 0, stream>>>(hchw, cwt + (size_t)(i * 3 + 2) * 36864,
                                       convb + (i * 3 + 2) * 64, yl2, 64, 4);
        // lowrank path (H2 overlays hchw — convs above already consumed it)
        k_mlp12<<<512, 256, 0, stream>>>(a, x,
                                         psiW1 + i * 192, psib1 + i * 64,
                                         psiW2 + i * 8192, psib2 + i * 128,
                                         phiW1 + i * 192, phib1 + i * 64,
                                         phiW2 + i * 8192, phib2 + i * 128,
                                         H2psi, H2phi);
        hipMemsetAsync(G, 0, (16384 + 128) * sizeof(float), stream);  // G + sv
        k_g<<<128, 256, 0, stream>>>(h, H2psi, G);
        k_sv<<<64, 256, 0, stream>>>(h, sv);
        k_yc<<<2, 256, 0, stream>>>(G, sv,
                                    psiW3 + (size_t)i * 32768, psib3 + i * 256,
                                    phiW3 + (size_t)i * 32768, phib3 + i * 256,
                                    C, D);
        k_x2c<<<128, 256, 0, stream>>>(H2phi, C, D, x2c);
        k_epilogue<<<8192, 256, 0, stream>>>(x1, yl1, yl2, x2c,
                                             lnG + i * 64, lnB + i * 64,
                                             h, hchw, (i < 3) ? 1 : 0);
    }

    k_head<<<512, 256, 0, stream>>>(h, q1t, q1b, q2W, q2b, (float*)d_out);
}

// Round 3
// 910.158 us; speedup vs baseline: 5.8749x; 2.7620x over previous
//
#include <hip/hip_runtime.h>
#include <cstddef>
#include <cstdint>

// ---------------- problem constants ----------------
// b=2, s=256, WIDTH=64, RANK=4, CLEVEL=1 (c=2), MLEVEL=2 (L=3), NB=4
// HID1=64, HID2=128

// ---------------- workspace layout (float offsets) ----------------
static constexpr size_t OFF_H      = 0;          // f32 NHWC h: 8388608
static constexpr size_t OFF_X1     = 8388608;    // 8388608
static constexpr size_t OFF_YL1    = 16777216;   // 2097152
static constexpr size_t OFF_YL2    = 18874368;   // 524288
static constexpr size_t OFF_HBF    = 19398656;   // bf16 NHWC h: 8388608 elems = 4194304 floats
static constexpr size_t OFF_H2PSI  = 23592960;   // 4194304 (x2c overlays here after k_g)
static constexpr size_t OFF_H2PHI  = 27787264;   // 4194304
static constexpr size_t OFF_CWTBF  = 31981568;   // 12*64*576 bf16 = 221184 floats
static constexpr size_t OFF_Q1T    = 32202752;   // 8192
static constexpr size_t OFF_G      = 32210944;   // 16384
static constexpr size_t OFF_SV     = 32227328;   // 128
static constexpr size_t OFF_C      = 32227456;   // 16384
static constexpr size_t OFF_D      = 32243840;   // 128
// end = 32243968 floats (~129 MB) <= proven-available 134.3 MB

typedef __attribute__((ext_vector_type(8)))  short bf16x8_t;   // 8 bf16 in 4 VGPRs
typedef __attribute__((ext_vector_type(16))) float f32x16_t;   // 32x32 MFMA acc

// ---------------- helpers ----------------
__device__ inline float wave_sum64(float v) {
    v += __shfl_xor(v, 1);
    v += __shfl_xor(v, 2);
    v += __shfl_xor(v, 4);
    v += __shfl_xor(v, 8);
    v += __shfl_xor(v, 16);
    v += __shfl_xor(v, 32);
    return v;
}

__device__ inline unsigned short f2bf(float f) {   // round-to-nearest-even
    uint32_t u = __float_as_uint(f);
    uint32_t r = u + 0x7FFFu + ((u >> 16) & 1u);
    return (unsigned short)(r >> 16);
}

// full-res flat pixel index of coarse pixel (b, n): n in [0,16384)
__device__ inline size_t fullpix(int b, int n) {
    return (size_t)(b * 65536 + (n >> 7) * 512 + ((n & 127) << 1));
}

struct Lerp { int i0, i1; float f; };
__device__ inline Lerp lcoord(int o, float r, float off, int Sin) {
    float s = fmaxf(fmaf((float)o, r, off), 0.f);
    Lerp L;
    L.i0 = (int)s;
    L.f  = s - (float)L.i0;
    L.i1 = min(L.i0 + 1, Sin - 1);
    return L;
}
__device__ inline float bilerp64(const float* __restrict__ base, int Sin,
                                 const Lerp& ly, const Lerp& lx, int lane) {
    float v00 = base[((size_t)(ly.i0 * Sin + lx.i0)) * 64 + lane];
    float v01 = base[((size_t)(ly.i0 * Sin + lx.i1)) * 64 + lane];
    float v10 = base[((size_t)(ly.i1 * Sin + lx.i0)) * 64 + lane];
    float v11 = base[((size_t)(ly.i1 * Sin + lx.i1)) * 64 + lane];
    float a = v00 + lx.f * (v01 - v00);
    float b = v10 + lx.f * (v11 - v10);
    return a + ly.f * (b - a);
}

// ---------------- weight transforms ----------------
// convW[i][l][oc][ic][3][3] f32 -> cwtbf[i*3+l][oc][tap*64+ic] bf16
__global__ __launch_bounds__(256) void k_transpose_convw_bf(const float* __restrict__ w,
                                                            unsigned short* __restrict__ wt) {
    int idx = blockIdx.x * 256 + threadIdx.x;     // 12*64*576 = 442368
    if (idx >= 442368) return;
    int k    = idx % 576;
    int rest = idx / 576;
    int oc   = rest & 63;
    int il   = rest >> 6;
    int tap  = k >> 6;
    int ic   = k & 63;
    wt[idx] = f2bf(w[((size_t)(il * 64 + oc) * 64 + ic) * 9 + tap]);
}
// q1W[64][128] -> q1t[128][64]
__global__ __launch_bounds__(256) void k_transpose_q1(const float* __restrict__ w,
                                                      float* __restrict__ wt) {
    int idx = blockIdx.x * 256 + threadIdx.x;     // 8192
    if (idx >= 8192) return;
    int k = idx & 63;
    int j = idx >> 6;
    wt[idx] = w[k * 128 + j];
}

// ---------------- lift: h = [a0,a1,x] @ pW + pb (writes f32 NHWC + bf16 NHWC) ----------------
__global__ __launch_bounds__(256) void k_lift(const float* __restrict__ x,
                                              const float* __restrict__ a,
                                              const float* __restrict__ pW,
                                              const float* __restrict__ pb,
                                              float* __restrict__ h,
                                              unsigned short* __restrict__ hbf) {
    int p = blockIdx.x * 256 + threadIdx.x;       // 131072
    float a0 = a[(size_t)p * 2 + 0];
    float a1 = a[(size_t)p * 2 + 1];
    float xv = x[p];
    float vals[64];
#pragma unroll
    for (int c = 0; c < 64; ++c)
        vals[c] = fmaf(a0, pW[c], fmaf(a1, pW[64 + c], fmaf(xv, pW[128 + c], pb[c])));
    float* hp = h + (size_t)p * 64;
#pragma unroll
    for (int c = 0; c < 64; c += 4)
        *(float4*)(hp + c) = make_float4(vals[c], vals[c + 1], vals[c + 2], vals[c + 3]);
    unsigned short us[64];
#pragma unroll
    for (int c = 0; c < 64; ++c) us[c] = f2bf(vals[c]);
    unsigned short* bp = hbf + (size_t)p * 64;
#pragma unroll
    for (int c = 0; c < 64; c += 8)
        *(uint4*)(bp + c) = *(uint4*)(us + c);
}

// ---------------- MFMA conv 3x3 SAME (64->64), all 3 levels in one grid ----------------
// A (input patches) in LDS pixel-major [18*18][64ic] bf16, XOR-swizzled.
// B (weights) in LDS [64oc][576k] bf16 (k = tap*64+ic), XOR-swizzled.
// Wave tile: 64 px x 64 oc via 2x2 frags of mfma_f32_32x32x16_bf16.
__global__ __launch_bounds__(256) void k_conv_mfma(
    const unsigned short* __restrict__ hbf,   // [2][256][256][64] bf16
    const unsigned short* __restrict__ wbf,   // [12][64][576] bf16
    const float* __restrict__ convb,          // [12][64]
    float* __restrict__ x1, float* __restrict__ yl1, float* __restrict__ yl2,
    int iter) {
    __shared__ unsigned short Ald[20736];     // 324 px * 64 ic  (41472 B)
    __shared__ unsigned short Bld[36864];     // 64 oc * 576 k   (73728 B)

    int bid = blockIdx.x;
    int lvl, tix, Sl, st, tpr;
    if (bid < 512)      { lvl = 0; tix = bid;       Sl = 256; st = 1; tpr = 16; }
    else if (bid < 640) { lvl = 1; tix = bid - 512; Sl = 128; st = 2; tpr = 8;  }
    else                { lvl = 2; tix = bid - 640; Sl = 64;  st = 4; tpr = 4;  }
    int tpb = tpr * tpr;
    int b = tix / tpb;
    int r = tix - b * tpb;
    int y0 = (r / tpr) * 16, x0 = (r % tpr) * 16;
    int t = threadIdx.x;

    // ---- stage A: 18x18 halo x 64 ic, zero-padded at image edges ----
    for (int c = t; c < 2592; c += 256) {       // 2592 = 324 rows * 8 slots(16B)
        int lin = c >> 3, slot = c & 7;
        int ty = lin / 18, tx = lin - ty * 18;
        int oy = y0 + ty - 1, ox = x0 + tx - 1;
        uint4 val = make_uint4(0u, 0u, 0u, 0u);
        if ((unsigned)oy < (unsigned)Sl && (unsigned)ox < (unsigned)Sl) {
            const unsigned short* src =
                hbf + (((size_t)(b * 256 + oy * st) * 256 + ox * st) << 6) + (slot << 3);
            val = *(const uint4*)src;
        }
        int byte = (lin << 7) + (((slot ^ (lin & 7))) << 4);
        *(uint4*)((char*)Ald + byte) = val;
    }
    // ---- stage B: weights for this (iter,lvl) ----
    {
        const unsigned short* wsrc = wbf + (size_t)(iter * 3 + lvl) * 36864;
        int oc = t >> 2, q = t & 3;
#pragma unroll
        for (int j = 0; j < 18; ++j) {
            int koff = q * 144 + j * 8;                 // bf16 elems
            uint4 v = *(const uint4*)(wsrc + oc * 576 + koff);
            int byte = (oc * 1152 + (koff << 1)) ^ ((oc & 7) << 4);
            *(uint4*)((char*)Bld + byte) = v;
        }
    }
    __syncthreads();

    // ---- compute ----
    int w    = t >> 6;
    int lane = t & 63;
    int lo   = lane & 31;
    int hi   = lane >> 5;
    f32x16_t acc00 = {}, acc01 = {}, acc10 = {}, acc11 = {};

    int yA0 = 4 * w + (lo >> 4);     // m=0 row-in-tile; m=1 adds 2
    int xA  = lo & 15;
#pragma unroll 3
    for (int tap = 0; tap < 9; ++tap) {
        int dy = tap / 3, dx = tap - dy * 3;
        int lin0 = (yA0 + dy) * 18 + (xA + dx);
        int lin1 = lin0 + 36;
#pragma unroll
        for (int kq = 0; kq < 4; ++kq) {
            int icb = (kq << 5) + (hi << 4);            // byte offset in A row
            int a0b = ((lin0 << 7) + icb) ^ ((lin0 & 7) << 4);
            int a1b = ((lin1 << 7) + icb) ^ ((lin1 & 7) << 4);
            bf16x8_t va0 = *(bf16x8_t*)((char*)Ald + a0b);
            bf16x8_t va1 = *(bf16x8_t*)((char*)Ald + a1b);
            int kk  = tap * 128 + icb;                  // byte offset in B row
            int b0b = (lo * 1152 + kk) ^ ((lo & 7) << 4);
            int b1b = ((lo + 32) * 1152 + kk) ^ ((lo & 7) << 4);
            bf16x8_t vb0 = *(bf16x8_t*)((char*)Bld + b0b);
            bf16x8_t vb1 = *(bf16x8_t*)((char*)Bld + b1b);
            acc00 = __builtin_amdgcn_mfma_f32_32x32x16_bf16(va0, vb0, acc00, 0, 0, 0);
            acc01 = __builtin_amdgcn_mfma_f32_32x32x16_bf16(va0, vb1, acc01, 0, 0, 0);
            acc10 = __builtin_amdgcn_mfma_f32_32x32x16_bf16(va1, vb0, acc10, 0, 0, 0);
            acc11 = __builtin_amdgcn_mfma_f32_32x32x16_bf16(va1, vb1, acc11, 0, 0, 0);
        }
    }

    // ---- store (C layout: col=lane&31 -> oc, row=(reg&3)+8*(reg>>2)+4*hi -> pixel) ----
    float* out = (lvl == 0) ? x1 : (lvl == 1 ? yl1 : yl2);
    const float* bias = convb + (iter * 3 + lvl) * 64;
    float bias0 = bias[lo];
    float bias1 = bias[32 + lo];
#pragma unroll
    for (int reg = 0; reg < 16; ++reg) {
        int row = (reg & 3) + 8 * (reg >> 2) + 4 * hi;
        int yt  = 4 * w + (row >> 4);
        int xt  = row & 15;
        size_t pix0 = ((size_t)(b * Sl + y0 + yt) * Sl + (x0 + xt)) << 6;
        out[pix0 + lo]      = acc00[reg] + bias0;
        out[pix0 + 32 + lo] = acc01[reg] + bias1;
        size_t pix1 = ((size_t)(b * Sl + y0 + yt + 2) * Sl + (x0 + xt)) << 6;
        out[pix1 + lo]      = acc10[reg] + bias0;
        out[pix1 + 32 + lo] = acc11[reg] + bias1;
    }
}

// ---------------- mlp12: H2 = relu(relu(a@W1+b1)@W2+b2) for psi AND phi ----------------
__global__ __launch_bounds__(256) void k_mlp12(
    const float* __restrict__ a, const float* __restrict__ x,
    const float* __restrict__ W1a, const float* __restrict__ b1a,
    const float* __restrict__ W2a, const float* __restrict__ b2a,
    const float* __restrict__ W1b, const float* __restrict__ b1b,
    const float* __restrict__ W2b, const float* __restrict__ b2b,
    float* __restrict__ H2a, float* __restrict__ H2b) {
    int blk = blockIdx.x;
    int m = blk >> 8;
    int t = threadIdx.x;
    int pxl = ((blk & 255) << 7) | (t & 127);      // 0..32767
    int j0 = __builtin_amdgcn_readfirstlane((t >> 7) << 6);
    const float* W1 = m ? W1b : W1a;
    const float* b1 = m ? b1b : b1a;
    const float* W2 = m ? W2b : W2a;
    const float* b2 = m ? b2b : b2a;
    float* H2 = m ? H2b : H2a;
    int b = pxl >> 14, n = pxl & 16383;
    size_t apix = fullpix(b, n);
    float a0 = a[apix * 2], a1 = a[apix * 2 + 1], xv = x[apix];

    float acc[64];
#pragma unroll
    for (int j = 0; j < 64; ++j) acc[j] = b2[j0 + j];
#pragma unroll 1
    for (int k = 0; k < 64; ++k) {
        float h1 = fmaxf(fmaf(a0, W1[k], fmaf(a1, W1[64 + k], fmaf(xv, W1[128 + k], b1[k]))), 0.f);
        const float* wr = W2 + k * 128 + j0;
#pragma unroll
        for (int j = 0; j < 64; ++j) acc[j] = fmaf(h1, wr[j], acc[j]);
    }
    float* op = H2 + (size_t)pxl * 128 + j0;
#pragma unroll
    for (int j = 0; j < 64; j += 4)
        *(float4*)(op + j) = make_float4(fmaxf(acc[j], 0.f), fmaxf(acc[j + 1], 0.f),
                                         fmaxf(acc[j + 2], 0.f), fmaxf(acc[j + 3], 0.f));
}

// ---------------- G[b][w][k] = sum_n v[n][w] * H2psi[n][k] ----------------
__global__ __launch_bounds__(256) void k_g(const float* __restrict__ h,
                                           const float* __restrict__ H2psi,
                                           float* __restrict__ G) {
    __shared__ float vt[16][64];
    __shared__ float h2t[16][128];
    int blk = blockIdx.x;            // 128: 64 per b
    int b = blk >> 6;
    int n0 = (blk & 63) << 8;
    int t = threadIdx.x;
    int wt = (t >> 5) << 3;
    int kt = (t & 31) << 2;
    float acc[8][4];
#pragma unroll
    for (int i = 0; i < 8; ++i)
#pragma unroll
        for (int j = 0; j < 4; ++j) acc[i][j] = 0.f;

    int pl = t >> 4;
    int w4 = (t & 15) << 2;
    int k8 = (t & 15) << 3;
    for (int c16 = 0; c16 < 16; ++c16) {
        int n = n0 + (c16 << 4) + pl;
        *(float4*)&vt[pl][w4] = *(const float4*)&h[fullpix(b, n) * 64 + w4];
        const float* hp = &H2psi[((size_t)(b * 16384 + n)) * 128 + k8];
        *(float4*)&h2t[pl][k8]     = *(const float4*)hp;
        *(float4*)&h2t[pl][k8 + 4] = *(const float4*)(hp + 4);
        __syncthreads();
#pragma unroll 4
        for (int nn = 0; nn < 16; ++nn) {
            float4 hv = *(float4*)&h2t[nn][kt];
            float4 v0 = *(float4*)&vt[nn][wt];
            float4 v1 = *(float4*)&vt[nn][wt + 4];
            float vv[8] = {v0.x, v0.y, v0.z, v0.w, v1.x, v1.y, v1.z, v1.w};
            float hh[4] = {hv.x, hv.y, hv.z, hv.w};
#pragma unroll
            for (int i = 0; i < 8; ++i)
#pragma unroll
                for (int j = 0; j < 4; ++j) acc[i][j] = fmaf(vv[i], hh[j], acc[i][j]);
        }
        __syncthreads();
    }
#pragma unroll
    for (int i = 0; i < 8; ++i)
#pragma unroll
        for (int j = 0; j < 4; ++j)
            atomicAdd(&G[((size_t)(b * 64 + wt + i)) * 128 + kt + j], acc[i][j]);
}

// ---------------- sv[b][w] = sum_n v[n][w] ----------------
__global__ __launch_bounds__(256) void k_sv(const float* __restrict__ h,
                                            float* __restrict__ sv) {
    __shared__ float red[4][64];
    int blk = blockIdx.x;            // 64: 32 per b
    int b = blk >> 5;
    int n0 = (blk & 31) << 9;
    int t = threadIdx.x;
    int w = t & 63, g = t >> 6;
    float s = 0.f;
    for (int q = 0; q < 128; ++q) {
        int n = n0 + (g << 7) + q;
        s += h[fullpix(b, n) * 64 + w];
    }
    red[g][w] = s;
    __syncthreads();
    if (t < 64) atomicAdd(&sv[b * 64 + t], red[0][t] + red[1][t] + red[2][t] + red[3][t]);
}

// ---------------- finalize: ybar -> c[b][w][k], d[b][w] ----------------
__global__ __launch_bounds__(256) void k_yc(const float* __restrict__ G,
                                            const float* __restrict__ sv,
                                            const float* __restrict__ W3psi,
                                            const float* __restrict__ b3psi,
                                            const float* __restrict__ W3phi,
                                            const float* __restrict__ b3phi,
                                            float* __restrict__ C,
                                            float* __restrict__ D) {
    __shared__ float ybar[256];
    int b = blockIdx.x;              // 2
    int t = threadIdx.x;
    {
        int o = t, w = o >> 2;
        float s = b3psi[o] * sv[b * 64 + w];
        const float* gp = &G[(size_t)(b * 64 + w) * 128];
#pragma unroll 4
        for (int k = 0; k < 128; ++k) s = fmaf(W3psi[k * 256 + o], gp[k], s);
        ybar[o] = s * (1.f / 16384.f);
    }
    __syncthreads();
    for (int rep = 0; rep < 32; ++rep) {
        int e = rep * 256 + t;       // 8192
        int w = e >> 7, k = e & 127;
        const float* wp = &W3phi[k * 256 + w * 4];
        C[b * 8192 + e] = fmaf(wp[0], ybar[w * 4],
                          fmaf(wp[1], ybar[w * 4 + 1],
                          fmaf(wp[2], ybar[w * 4 + 2], wp[3] * ybar[w * 4 + 3])));
    }
    if (t < 64) {
        int w = t;
        D[b * 64 + w] = b3phi[w * 4] * ybar[w * 4] + b3phi[w * 4 + 1] * ybar[w * 4 + 1]
                      + b3phi[w * 4 + 2] * ybar[w * 4 + 2] + b3phi[w * 4 + 3] * ybar[w * 4 + 3];
    }
}

// ---------------- x2c[px][w] = H2phi[px][:] . c[b][w][:] + d[b][w] ----------------
__global__ __launch_bounds__(256) void k_x2c(const float* __restrict__ H2phi,
                                             const float* __restrict__ C,
                                             const float* __restrict__ D,
                                             float* __restrict__ x2c) {
    __shared__ float cl[8192];
    int blk = blockIdx.x;            // 128
    int b = blk >> 6;
    int px0 = blk << 8;
    int t = threadIdx.x;
    const float* cp = C + b * 8192;
#pragma unroll
    for (int rep = 0; rep < 8; ++rep) {
        int f = rep * 1024 + t * 4;
        *(float4*)&cl[f] = *(const float4*)&cp[f];
    }
    __syncthreads();

    int w0 = __builtin_amdgcn_readfirstlane((t >> 6) << 4);
    int px = px0 + ((t & 63) << 2);
    float acc[4][16];
#pragma unroll
    for (int i = 0; i < 4; ++i)
#pragma unroll
        for (int j = 0; j < 16; ++j) acc[i][j] = 0.f;

    const float* hbase = H2phi + (size_t)px * 128;
#pragma unroll 2
    for (int kq = 0; kq < 32; ++kq) {
        float4 h2q[4];
#pragma unroll
        for (int i = 0; i < 4; ++i) h2q[i] = *(const float4*)&hbase[i * 128 + kq * 4];
#pragma unroll
        for (int j = 0; j < 16; ++j) {
            float4 cq = *(float4*)&cl[(w0 + j) * 128 + kq * 4];
#pragma unroll
            for (int i = 0; i < 4; ++i) {
                acc[i][j] = fmaf(h2q[i].x, cq.x, acc[i][j]);
                acc[i][j] = fmaf(h2q[i].y, cq.y, acc[i][j]);
                acc[i][j] = fmaf(h2q[i].z, cq.z, acc[i][j]);
                acc[i][j] = fmaf(h2q[i].w, cq.w, acc[i][j]);
            }
        }
    }
#pragma unroll
    for (int i = 0; i < 4; ++i) {
        float* op = &x2c[(size_t)(px + i) * 64 + w0];
#pragma unroll
        for (int j = 0; j < 16; j += 4) {
            float4 o4 = make_float4(acc[i][j]     + D[b * 64 + w0 + j],
                                    acc[i][j + 1] + D[b * 64 + w0 + j + 1],
                                    acc[i][j + 2] + D[b * 64 + w0 + j + 2],
                                    acc[i][j + 3] + D[b * 64 + w0 + j + 3]);
            *(float4*)(op + j) = o4;
        }
    }
}

// ---------------- epilogue: h = LN(x1 + up(yl1) + up(yl2) + up(x2c)); writes f32 + bf16 ----------------
__global__ __launch_bounds__(256) void k_epilogue(const float* __restrict__ x1,
                                                  const float* __restrict__ yl1,
                                                  const float* __restrict__ yl2,
                                                  const float* __restrict__ x2c,
                                                  const float* __restrict__ lnG,
                                                  const float* __restrict__ lnB,
                                                  float* __restrict__ h,
                                                  unsigned short* __restrict__ hbf,
                                                  int do_relu) {
    int t    = threadIdx.x;
    int blk  = blockIdx.x;                 // 8192 = 2 * 256 * 16
    int b    = blk >> 12;
    int rest = blk & 4095;
    int y    = rest >> 4;
    int x0   = (rest & 15) << 4;
    int wv = t >> 6, lane = t & 63;

    float g = lnG[lane], be = lnB[lane];
    const float* Y1 = yl1 + (size_t)b * 16384 * 64;
    const float* Y2 = yl2 + (size_t)b * 4096 * 64;
    const float* XC = x2c + (size_t)b * 16384 * 64;

    for (int pp = 0; pp < 4; ++pp) {
        int xx = x0 + wv * 4 + pp;
        size_t pix = (size_t)((b * 256 + y) * 256 + xx);
        float v = x1[pix * 64 + lane];
        {
            Lerp ly = lcoord(y, 0.5f, -0.25f, 128);
            Lerp lx = lcoord(xx, 0.5f, -0.25f, 128);
            v += bilerp64(Y1, 128, ly, lx, lane);
        }
        {
            Lerp ly = lcoord(y, 0.25f, -0.375f, 64);
            Lerp lx = lcoord(xx, 0.25f, -0.375f, 64);
            v += bilerp64(Y2, 64, ly, lx, lane);
        }
        {
            Lerp ly = lcoord(y, 0.5f, -0.25f, 128);
            Lerp lx = lcoord(xx, 0.5f, -0.25f, 128);
            v += bilerp64(XC, 128, ly, lx, lane);
        }
        float mu  = wave_sum64(v) * (1.f / 64.f);
        float d   = v - mu;
        float var = wave_sum64(d * d) * (1.f / 64.f);
        float ov  = fmaf(d * rsqrtf(var + 1e-5f), g, be);
        if (do_relu) ov = fmaxf(ov, 0.f);
        h[pix * 64 + lane]   = ov;
        hbf[pix * 64 + lane] = f2bf(ov);
    }
}

// ---------------- head ----------------
__global__ __launch_bounds__(256) void k_head(const float* __restrict__ h,
                                              const float* __restrict__ q1t,
                                              const float* __restrict__ q1b,
                                              const float* __restrict__ q2,
                                              const float* __restrict__ q2b,
                                              float* __restrict__ out) {
    int p = blockIdx.x * 256 + threadIdx.x;   // 131072
    float hv[64];
    const float* hp = h + (size_t)p * 64;
#pragma unroll
    for (int w = 0; w < 64; w += 4) {
        float4 t4 = *(const float4*)(hp + w);
        hv[w] = t4.x; hv[w + 1] = t4.y; hv[w + 2] = t4.z; hv[w + 3] = t4.w;
    }
    float o = q2b[0];
#pragma unroll 1
    for (int j = 0; j < 128; ++j) {
        const float* r = q1t + j * 64;
        float s0 = 0.f, s1 = 0.f, s2 = 0.f, s3 = 0.f;
#pragma unroll
        for (int w = 0; w < 64; w += 4) {
            s0 = fmaf(hv[w],     r[w],     s0);
            s1 = fmaf(hv[w + 1], r[w + 1], s1);
            s2 = fmaf(hv[w + 2], r[w + 2], s2);
            s3 = fmaf(hv[w + 3], r[w + 3], s3);
        }
        float s = ((s0 + s1) + (s2 + s3)) + q1b[j];
        o = fmaf(fmaxf(s, 0.f), q2[j], o);
    }
    out[p] = o;
}

// ---------------- launch ----------------
extern "C" void kernel_launch(void* const* d_in, const int* in_sizes, int n_in,
                              void* d_out, int out_size, void* d_ws, size_t ws_size,
                              hipStream_t stream) {
    const float* x     = (const float*)d_in[0];
    const float* a     = (const float*)d_in[1];
    const float* pW    = (const float*)d_in[2];
    const float* pb    = (const float*)d_in[3];
    const float* q1W   = (const float*)d_in[4];
    const float* q1b   = (const float*)d_in[5];
    const float* q2W   = (const float*)d_in[6];
    const float* q2b   = (const float*)d_in[7];
    const float* phiW1 = (const float*)d_in[8];
    const float* phib1 = (const float*)d_in[9];
    const float* phiW2 = (const float*)d_in[10];
    const float* phib2 = (const float*)d_in[11];
    const float* phiW3 = (const float*)d_in[12];
    const float* phib3 = (const float*)d_in[13];
    const float* psiW1 = (const float*)d_in[14];
    const float* psib1 = (const float*)d_in[15];
    const float* psiW2 = (const float*)d_in[16];
    const float* psib2 = (const float*)d_in[17];
    const float* psiW3 = (const float*)d_in[18];
    const float* psib3 = (const float*)d_in[19];
    const float* lnG   = (const float*)d_in[20];
    const float* lnB   = (const float*)d_in[21];
    const float* convW = (const float*)d_in[22];
    const float* convb = (const float*)d_in[23];

    float* ws    = (float*)d_ws;
    float* h     = ws + OFF_H;
    float* x1    = ws + OFF_X1;
    float* yl1   = ws + OFF_YL1;
    float* yl2   = ws + OFF_YL2;
    unsigned short* hbf = (unsigned short*)(ws + OFF_HBF);
    float* H2psi = ws + OFF_H2PSI;
    float* x2c   = ws + OFF_H2PSI;            // overlay: H2psi dead after k_g
    float* H2phi = ws + OFF_H2PHI;
    unsigned short* cwtbf = (unsigned short*)(ws + OFF_CWTBF);
    float* q1t   = ws + OFF_Q1T;
    float* G     = ws + OFF_G;
    float* sv    = ws + OFF_SV;
    float* C     = ws + OFF_C;
    float* D     = ws + OFF_D;

    k_transpose_convw_bf<<<1728, 256, 0, stream>>>(convW, cwtbf);
    k_transpose_q1<<<32, 256, 0, stream>>>(q1W, q1t);

    k_lift<<<512, 256, 0, stream>>>(x, a, pW, pb, h, hbf);

    for (int i = 0; i < 4; ++i) {
        k_conv_mfma<<<672, 256, 0, stream>>>(hbf, cwtbf, convb, x1, yl1, yl2, i);

        k_mlp12<<<512, 256, 0, stream>>>(a, x,
                                         psiW1 + i * 192, psib1 + i * 64,
                                         psiW2 + i * 8192, psib2 + i * 128,
                                         phiW1 + i * 192, phib1 + i * 64,
                                         phiW2 + i * 8192, phib2 + i * 128,
                                         H2psi, H2phi);
        hipMemsetAsync(G, 0, (16384 + 128) * sizeof(float), stream);  // G + sv
        k_g<<<128, 256, 0, stream>>>(h, H2psi, G);
        k_sv<<<64, 256, 0, stream>>>(h, sv);
        k_yc<<<2, 256, 0, stream>>>(G, sv,
                                    psiW3 + (size_t)i * 32768, psib3 + i * 256,
                                    phiW3 + (size_t)i * 32768, phib3 + i * 256,
                                    C, D);
        k_x2c<<<128, 256, 0, stream>>>(H2phi, C, D, x2c);
        k_epilogue<<<8192, 256, 0, stream>>>(x1, yl1, yl2, x2c,
                                             lnG + i * 64, lnB + i * 64,
                                             h, hbf, (i < 3) ? 1 : 0);
    }

    k_head<<<512, 256, 0, stream>>>(h, q1t, q1b, q2W, q2b, (float*)d_out);
}

// Round 4
// 796.159 us; speedup vs baseline: 6.7161x; 1.1432x over previous
//
#include <hip/hip_runtime.h>
#include <cstddef>
#include <cstdint>

// ---------------- problem constants ----------------
// b=2, s=256, WIDTH=64, RANK=4, CLEVEL=1 (c=2), MLEVEL=2 (L=3), NB=4
// HID1=64, HID2=128

// ---------------- workspace layout (float offsets) ----------------
static constexpr size_t OFF_H      = 0;          // f32 NHWC h: 8388608
static constexpr size_t OFF_X1     = 8388608;    // 8388608
static constexpr size_t OFF_YL1    = 16777216;   // 2097152
static constexpr size_t OFF_YL2    = 18874368;   // 524288
static constexpr size_t OFF_HBF    = 19398656;   // bf16 NHWC h: 8388608 elems = 4194304 floats
static constexpr size_t OFF_H2PSI  = 23592960;   // 4194304 (x2c overlays here after k_g)
static constexpr size_t OFF_H2PHI  = 27787264;   // 4194304
static constexpr size_t OFF_CWTBF  = 31981568;   // 12*64*576 bf16 = 221184 floats
static constexpr size_t OFF_Q1BF   = 32202752;   // 8192 bf16 = 4096 floats
static constexpr size_t OFF_G      = 32210944;   // 16384
static constexpr size_t OFF_SV     = 32227328;   // 128
static constexpr size_t OFF_C      = 32227456;   // 16384
static constexpr size_t OFF_D      = 32243840;   // 128
// end = 32243968 floats (~129 MB) <= proven-available 134.3 MB

typedef __attribute__((ext_vector_type(8)))  short bf16x8_t;   // 8 bf16 in 4 VGPRs
typedef __attribute__((ext_vector_type(16))) float f32x16_t;   // 32x32 MFMA acc

// ---------------- helpers ----------------
__device__ inline float wave_sum64(float v) {
    v += __shfl_xor(v, 1);
    v += __shfl_xor(v, 2);
    v += __shfl_xor(v, 4);
    v += __shfl_xor(v, 8);
    v += __shfl_xor(v, 16);
    v += __shfl_xor(v, 32);
    return v;
}

__device__ inline unsigned short f2bf(float f) {   // round-to-nearest-even
    uint32_t u = __float_as_uint(f);
    uint32_t r = u + 0x7FFFu + ((u >> 16) & 1u);
    return (unsigned short)(r >> 16);
}

// full-res flat pixel index of coarse pixel (b, n): n in [0,16384)
__device__ inline size_t fullpix(int b, int n) {
    return (size_t)(b * 65536 + (n >> 7) * 512 + ((n & 127) << 1));
}

struct Lerp { int i0, i1; float f; };
__device__ inline Lerp lcoord(int o, float r, float off, int Sin) {
    float s = fmaxf(fmaf((float)o, r, off), 0.f);
    Lerp L;
    L.i0 = (int)s;
    L.f  = s - (float)L.i0;
    L.i1 = min(L.i0 + 1, Sin - 1);
    return L;
}
__device__ inline float bilerp64(const float* __restrict__ base, int Sin,
                                 const Lerp& ly, const Lerp& lx, int lane) {
    float v00 = base[((size_t)(ly.i0 * Sin + lx.i0)) * 64 + lane];
    float v01 = base[((size_t)(ly.i0 * Sin + lx.i1)) * 64 + lane];
    float v10 = base[((size_t)(ly.i1 * Sin + lx.i0)) * 64 + lane];
    float v11 = base[((size_t)(ly.i1 * Sin + lx.i1)) * 64 + lane];
    float a = v00 + lx.f * (v01 - v00);
    float b = v10 + lx.f * (v11 - v10);
    return a + ly.f * (b - a);
}

// ---------------- weight transforms ----------------
// convW[i][l][oc][ic][3][3] f32 -> cwtbf[i*3+l][oc][tap*64+ic] bf16
__global__ __launch_bounds__(256) void k_transpose_convw_bf(const float* __restrict__ w,
                                                            unsigned short* __restrict__ wt) {
    int idx = blockIdx.x * 256 + threadIdx.x;     // 12*64*576 = 442368
    if (idx >= 442368) return;
    int k    = idx % 576;
    int rest = idx / 576;
    int oc   = rest & 63;
    int il   = rest >> 6;
    int tap  = k >> 6;
    int ic   = k & 63;
    wt[idx] = f2bf(w[((size_t)(il * 64 + oc) * 64 + ic) * 9 + tap]);
}
// q1W[64][128] f32 -> q1bf[j][k] bf16 (transposed)
__global__ __launch_bounds__(256) void k_transpose_q1bf(const float* __restrict__ w,
                                                        unsigned short* __restrict__ wt) {
    int idx = blockIdx.x * 256 + threadIdx.x;     // 8192
    if (idx >= 8192) return;
    int k = idx & 63;
    int j = idx >> 6;
    wt[j * 64 + k] = f2bf(w[k * 128 + j]);
}

// ---------------- lift: h = [a0,a1,x] @ pW + pb (writes f32 NHWC + bf16 NHWC) ----------------
__global__ __launch_bounds__(256) void k_lift(const float* __restrict__ x,
                                              const float* __restrict__ a,
                                              const float* __restrict__ pW,
                                              const float* __restrict__ pb,
                                              float* __restrict__ h,
                                              unsigned short* __restrict__ hbf) {
    int p = blockIdx.x * 256 + threadIdx.x;       // 131072
    float a0 = a[(size_t)p * 2 + 0];
    float a1 = a[(size_t)p * 2 + 1];
    float xv = x[p];
    float vals[64];
#pragma unroll
    for (int c = 0; c < 64; ++c)
        vals[c] = fmaf(a0, pW[c], fmaf(a1, pW[64 + c], fmaf(xv, pW[128 + c], pb[c])));
    float* hp = h + (size_t)p * 64;
#pragma unroll
    for (int c = 0; c < 64; c += 4)
        *(float4*)(hp + c) = make_float4(vals[c], vals[c + 1], vals[c + 2], vals[c + 3]);
    unsigned short us[64];
#pragma unroll
    for (int c = 0; c < 64; ++c) us[c] = f2bf(vals[c]);
    unsigned short* bp = hbf + (size_t)p * 64;
#pragma unroll
    for (int c = 0; c < 64; c += 8)
        *(uint4*)(bp + c) = *(uint4*)(us + c);
}

// ---------------- MFMA conv 3x3 SAME (64->64), all 3 levels in one grid ----------------
__global__ __launch_bounds__(256) void k_conv_mfma(
    const unsigned short* __restrict__ hbf,   // [2][256][256][64] bf16
    const unsigned short* __restrict__ wbf,   // [12][64][576] bf16
    const float* __restrict__ convb,          // [12][64]
    float* __restrict__ x1, float* __restrict__ yl1, float* __restrict__ yl2,
    int iter) {
    __shared__ unsigned short Ald[20736];     // 324 px * 64 ic  (41472 B)
    __shared__ unsigned short Bld[36864];     // 64 oc * 576 k   (73728 B)

    int bid = blockIdx.x;
    int lvl, tix, Sl, st, tpr;
    if (bid < 512)      { lvl = 0; tix = bid;       Sl = 256; st = 1; tpr = 16; }
    else if (bid < 640) { lvl = 1; tix = bid - 512; Sl = 128; st = 2; tpr = 8;  }
    else                { lvl = 2; tix = bid - 640; Sl = 64;  st = 4; tpr = 4;  }
    int tpb = tpr * tpr;
    int b = tix / tpb;
    int r = tix - b * tpb;
    int y0 = (r / tpr) * 16, x0 = (r % tpr) * 16;
    int t = threadIdx.x;

    // ---- stage A: 18x18 halo x 64 ic, zero-padded at image edges ----
    for (int c = t; c < 2592; c += 256) {       // 2592 = 324 rows * 8 slots(16B)
        int lin = c >> 3, slot = c & 7;
        int ty = lin / 18, tx = lin - ty * 18;
        int oy = y0 + ty - 1, ox = x0 + tx - 1;
        uint4 val = make_uint4(0u, 0u, 0u, 0u);
        if ((unsigned)oy < (unsigned)Sl && (unsigned)ox < (unsigned)Sl) {
            const unsigned short* src =
                hbf + (((size_t)(b * 256 + oy * st) * 256 + ox * st) << 6) + (slot << 3);
            val = *(const uint4*)src;
        }
        int byte = (lin << 7) + (((slot ^ (lin & 7))) << 4);
        *(uint4*)((char*)Ald + byte) = val;
    }
    // ---- stage B: weights for this (iter,lvl) ----
    {
        const unsigned short* wsrc = wbf + (size_t)(iter * 3 + lvl) * 36864;
        int oc = t >> 2, q = t & 3;
#pragma unroll
        for (int j = 0; j < 18; ++j) {
            int koff = q * 144 + j * 8;                 // bf16 elems
            uint4 v = *(const uint4*)(wsrc + oc * 576 + koff);
            int byte = (oc * 1152 + (koff << 1)) ^ ((oc & 7) << 4);
            *(uint4*)((char*)Bld + byte) = v;
        }
    }
    __syncthreads();

    // ---- compute ----
    int w    = t >> 6;
    int lane = t & 63;
    int lo   = lane & 31;
    int hi   = lane >> 5;
    f32x16_t acc00 = {}, acc01 = {}, acc10 = {}, acc11 = {};

    int yA0 = 4 * w + (lo >> 4);
    int xA  = lo & 15;
#pragma unroll 3
    for (int tap = 0; tap < 9; ++tap) {
        int dy = tap / 3, dx = tap - dy * 3;
        int lin0 = (yA0 + dy) * 18 + (xA + dx);
        int lin1 = lin0 + 36;
#pragma unroll
        for (int kq = 0; kq < 4; ++kq) {
            int icb = (kq << 5) + (hi << 4);
            int a0b = ((lin0 << 7) + icb) ^ ((lin0 & 7) << 4);
            int a1b = ((lin1 << 7) + icb) ^ ((lin1 & 7) << 4);
            bf16x8_t va0 = *(bf16x8_t*)((char*)Ald + a0b);
            bf16x8_t va1 = *(bf16x8_t*)((char*)Ald + a1b);
            int kk  = tap * 128 + icb;
            int b0b = (lo * 1152 + kk) ^ ((lo & 7) << 4);
            int b1b = ((lo + 32) * 1152 + kk) ^ ((lo & 7) << 4);
            bf16x8_t vb0 = *(bf16x8_t*)((char*)Bld + b0b);
            bf16x8_t vb1 = *(bf16x8_t*)((char*)Bld + b1b);
            acc00 = __builtin_amdgcn_mfma_f32_32x32x16_bf16(va0, vb0, acc00, 0, 0, 0);
            acc01 = __builtin_amdgcn_mfma_f32_32x32x16_bf16(va0, vb1, acc01, 0, 0, 0);
            acc10 = __builtin_amdgcn_mfma_f32_32x32x16_bf16(va1, vb0, acc10, 0, 0, 0);
            acc11 = __builtin_amdgcn_mfma_f32_32x32x16_bf16(va1, vb1, acc11, 0, 0, 0);
        }
    }

    // ---- store ----
    float* out = (lvl == 0) ? x1 : (lvl == 1 ? yl1 : yl2);
    const float* bias = convb + (iter * 3 + lvl) * 64;
    float bias0 = bias[lo];
    float bias1 = bias[32 + lo];
#pragma unroll
    for (int reg = 0; reg < 16; ++reg) {
        int row = (reg & 3) + 8 * (reg >> 2) + 4 * hi;
        int yt  = 4 * w + (row >> 4);
        int xt  = row & 15;
        size_t pix0 = ((size_t)(b * Sl + y0 + yt) * Sl + (x0 + xt)) << 6;
        out[pix0 + lo]      = acc00[reg] + bias0;
        out[pix0 + 32 + lo] = acc01[reg] + bias1;
        size_t pix1 = ((size_t)(b * Sl + y0 + yt + 2) * Sl + (x0 + xt)) << 6;
        out[pix1 + lo]      = acc10[reg] + bias0;
        out[pix1 + 32 + lo] = acc11[reg] + bias1;
    }
}

// ---------------- mlp12: H2 = relu(relu(a@W1+b1)@W2+b2), 4 threads/px ----------------
__global__ __launch_bounds__(256) void k_mlp12(
    const float* __restrict__ a, const float* __restrict__ x,
    const float* __restrict__ W1a, const float* __restrict__ b1a,
    const float* __restrict__ W2a, const float* __restrict__ b2a,
    const float* __restrict__ W1b, const float* __restrict__ b1b,
    const float* __restrict__ W2b, const float* __restrict__ b2b,
    float* __restrict__ H2a, float* __restrict__ H2b) {
    int blk = blockIdx.x;                          // 1024
    int m = blk >> 9;
    int t = threadIdx.x;
    int pxl = ((blk & 511) << 6) | (t & 63);       // 0..32767
    int j0 = __builtin_amdgcn_readfirstlane((t >> 6) << 5);  // 0/32/64/96
    const float* W1 = m ? W1b : W1a;
    const float* b1 = m ? b1b : b1a;
    const float* W2 = m ? W2b : W2a;
    const float* b2 = m ? b2b : b2a;
    float* H2 = m ? H2b : H2a;
    int b = pxl >> 14, n = pxl & 16383;
    size_t apix = fullpix(b, n);
    float a0 = a[apix * 2], a1 = a[apix * 2 + 1], xv = x[apix];

    float acc[32];
#pragma unroll
    for (int j = 0; j < 32; ++j) acc[j] = b2[j0 + j];
#pragma unroll 1
    for (int k = 0; k < 64; ++k) {
        float h1 = fmaxf(fmaf(a0, W1[k], fmaf(a1, W1[64 + k], fmaf(xv, W1[128 + k], b1[k]))), 0.f);
        const float* wr = W2 + k * 128 + j0;
#pragma unroll
        for (int j = 0; j < 32; ++j) acc[j] = fmaf(h1, wr[j], acc[j]);
    }
    float* op = H2 + (size_t)pxl * 128 + j0;
#pragma unroll
    for (int j = 0; j < 32; j += 4)
        *(float4*)(op + j) = make_float4(fmaxf(acc[j], 0.f), fmaxf(acc[j + 1], 0.f),
                                         fmaxf(acc[j + 2], 0.f), fmaxf(acc[j + 3], 0.f));
}

// ---------------- G[b][w][k] = sum_n v[n][w]*H2psi[n][k]; also sv[b][w] = sum_n v[n][w] ----------------
__global__ __launch_bounds__(256) void k_g(const float* __restrict__ h,
                                           const float* __restrict__ H2psi,
                                           float* __restrict__ G,
                                           float* __restrict__ sv) {
    __shared__ float vt[16][64];
    __shared__ float h2t[16][128];
    int blk = blockIdx.x;            // 128: 64 per b
    int b = blk >> 6;
    int n0 = (blk & 63) << 8;
    int t = threadIdx.x;
    int wt_ = (t >> 5) << 3;
    int kt = (t & 31) << 2;
    float acc[8][4];
#pragma unroll
    for (int i = 0; i < 8; ++i)
#pragma unroll
        for (int j = 0; j < 4; ++j) acc[i][j] = 0.f;
    float svp0 = 0.f, svp1 = 0.f, svp2 = 0.f, svp3 = 0.f;

    int pl = t >> 4;
    int w4 = (t & 15) << 2;
    int k8 = (t & 15) << 3;
    for (int c16 = 0; c16 < 16; ++c16) {
        int n = n0 + (c16 << 4) + pl;
        float4 v4 = *(const float4*)&h[fullpix(b, n) * 64 + w4];
        *(float4*)&vt[pl][w4] = v4;
        svp0 += v4.x; svp1 += v4.y; svp2 += v4.z; svp3 += v4.w;
        const float* hp = &H2psi[((size_t)(b * 16384 + n)) * 128 + k8];
        *(float4*)&h2t[pl][k8]     = *(const float4*)hp;
        *(float4*)&h2t[pl][k8 + 4] = *(const float4*)(hp + 4);
        __syncthreads();
#pragma unroll 4
        for (int nn = 0; nn < 16; ++nn) {
            float4 hv = *(float4*)&h2t[nn][kt];
            float4 v0 = *(float4*)&vt[nn][wt_];
            float4 v1 = *(float4*)&vt[nn][wt_ + 4];
            float vv[8] = {v0.x, v0.y, v0.z, v0.w, v1.x, v1.y, v1.z, v1.w};
            float hh[4] = {hv.x, hv.y, hv.z, hv.w};
#pragma unroll
            for (int i = 0; i < 8; ++i)
#pragma unroll
                for (int j = 0; j < 4; ++j) acc[i][j] = fmaf(vv[i], hh[j], acc[i][j]);
        }
        __syncthreads();
    }
    // sv reduction (reuse vt)
    vt[pl][w4] = svp0; vt[pl][w4 + 1] = svp1; vt[pl][w4 + 2] = svp2; vt[pl][w4 + 3] = svp3;
    __syncthreads();
    if (t < 64) {
        float s = 0.f;
#pragma unroll
        for (int rr = 0; rr < 16; ++rr) s += vt[rr][t];
        atomicAdd(&sv[b * 64 + t], s);
    }
#pragma unroll
    for (int i = 0; i < 8; ++i)
#pragma unroll
        for (int j = 0; j < 4; ++j)
            atomicAdd(&G[((size_t)(b * 64 + wt_ + i)) * 128 + kt + j], acc[i][j]);
}

// ---------------- finalize: ybar -> c[b][w][k], d[b][w] ----------------
__global__ __launch_bounds__(256) void k_yc(const float* __restrict__ G,
                                            const float* __restrict__ sv,
                                            const float* __restrict__ W3psi,
                                            const float* __restrict__ b3psi,
                                            const float* __restrict__ W3phi,
                                            const float* __restrict__ b3phi,
                                            float* __restrict__ C,
                                            float* __restrict__ D) {
    __shared__ float ybar[256];
    int b = blockIdx.x;              // 2
    int t = threadIdx.x;
    {
        int o = t, w = o >> 2;
        float s = b3psi[o] * sv[b * 64 + w];
        const float* gp = &G[(size_t)(b * 64 + w) * 128];
#pragma unroll 4
        for (int k = 0; k < 128; ++k) s = fmaf(W3psi[k * 256 + o], gp[k], s);
        ybar[o] = s * (1.f / 16384.f);
    }
    __syncthreads();
    for (int rep = 0; rep < 32; ++rep) {
        int e = rep * 256 + t;       // 8192
        int w = e >> 7, k = e & 127;
        const float* wp = &W3phi[k * 256 + w * 4];
        C[b * 8192 + e] = fmaf(wp[0], ybar[w * 4],
                          fmaf(wp[1], ybar[w * 4 + 1],
                          fmaf(wp[2], ybar[w * 4 + 2], wp[3] * ybar[w * 4 + 3])));
    }
    if (t < 64) {
        int w = t;
        D[b * 64 + w] = b3phi[w * 4] * ybar[w * 4] + b3phi[w * 4 + 1] * ybar[w * 4 + 1]
                      + b3phi[w * 4 + 2] * ybar[w * 4 + 2] + b3phi[w * 4 + 3] * ybar[w * 4 + 3];
    }
}

// ---------------- x2c[px][w] = H2phi[px][:] . c[b][w][:] + d[b][w] ----------------
__global__ __launch_bounds__(256) void k_x2c(const float* __restrict__ H2phi,
                                             const float* __restrict__ C,
                                             const float* __restrict__ D,
                                             float* __restrict__ x2c) {
    __shared__ float cl[8192];
    int blk = blockIdx.x;            // 128
    int b = blk >> 6;
    int px0 = blk << 8;
    int t = threadIdx.x;
    const float* cp = C + b * 8192;
#pragma unroll
    for (int rep = 0; rep < 8; ++rep) {
        int f = rep * 1024 + t * 4;
        *(float4*)&cl[f] = *(const float4*)&cp[f];
    }
    __syncthreads();

    int w0 = __builtin_amdgcn_readfirstlane((t >> 6) << 4);
    int px = px0 + ((t & 63) << 2);
    float acc[4][16];
#pragma unroll
    for (int i = 0; i < 4; ++i)
#pragma unroll
        for (int j = 0; j < 16; ++j) acc[i][j] = 0.f;

    const float* hbase = H2phi + (size_t)px * 128;
#pragma unroll 2
    for (int kq = 0; kq < 32; ++kq) {
        float4 h2q[4];
#pragma unroll
        for (int i = 0; i < 4; ++i) h2q[i] = *(const float4*)&hbase[i * 128 + kq * 4];
#pragma unroll
        for (int j = 0; j < 16; ++j) {
            float4 cq = *(float4*)&cl[(w0 + j) * 128 + kq * 4];
#pragma unroll
            for (int i = 0; i < 4; ++i) {
                acc[i][j] = fmaf(h2q[i].x, cq.x, acc[i][j]);
                acc[i][j] = fmaf(h2q[i].y, cq.y, acc[i][j]);
                acc[i][j] = fmaf(h2q[i].z, cq.z, acc[i][j]);
                acc[i][j] = fmaf(h2q[i].w, cq.w, acc[i][j]);
            }
        }
    }
#pragma unroll
    for (int i = 0; i < 4; ++i) {
        float* op = &x2c[(size_t)(px + i) * 64 + w0];
#pragma unroll
        for (int j = 0; j < 16; j += 4) {
            float4 o4 = make_float4(acc[i][j]     + D[b * 64 + w0 + j],
                                    acc[i][j + 1] + D[b * 64 + w0 + j + 1],
                                    acc[i][j + 2] + D[b * 64 + w0 + j + 2],
                                    acc[i][j + 3] + D[b * 64 + w0 + j + 3]);
            *(float4*)(op + j) = o4;
        }
    }
}

// ---------------- epilogue: h = LN(x1 + up(yl1) + up(yl2) + up(x2c)); writes f32 + bf16 ----------------
__global__ __launch_bounds__(256) void k_epilogue(const float* __restrict__ x1,
                                                  const float* __restrict__ yl1,
                                                  const float* __restrict__ yl2,
                                                  const float* __restrict__ x2c,
                                                  const float* __restrict__ lnG,
                                                  const float* __restrict__ lnB,
                                                  float* __restrict__ h,
                                                  unsigned short* __restrict__ hbf,
                                                  int do_relu) {
    int t    = threadIdx.x;
    int blk  = blockIdx.x;                 // 8192 = 2 * 256 * 16
    int b    = blk >> 12;
    int rest = blk & 4095;
    int y    = rest >> 4;
    int x0   = (rest & 15) << 4;
    int wv = t >> 6, lane = t & 63;

    float g = lnG[lane], be = lnB[lane];
    const float* Y1 = yl1 + (size_t)b * 16384 * 64;
    const float* Y2 = yl2 + (size_t)b * 4096 * 64;
    const float* XC = x2c + (size_t)b * 16384 * 64;

    for (int pp = 0; pp < 4; ++pp) {
        int xx = x0 + wv * 4 + pp;
        size_t pix = (size_t)((b * 256 + y) * 256 + xx);
        float v = x1[pix * 64 + lane];
        {
            Lerp ly = lcoord(y, 0.5f, -0.25f, 128);
            Lerp lx = lcoord(xx, 0.5f, -0.25f, 128);
            v += bilerp64(Y1, 128, ly, lx, lane);
        }
        {
            Lerp ly = lcoord(y, 0.25f, -0.375f, 64);
            Lerp lx = lcoord(xx, 0.25f, -0.375f, 64);
            v += bilerp64(Y2, 64, ly, lx, lane);
        }
        {
            Lerp ly = lcoord(y, 0.5f, -0.25f, 128);
            Lerp lx = lcoord(xx, 0.5f, -0.25f, 128);
            v += bilerp64(XC, 128, ly, lx, lane);
        }
        float mu  = wave_sum64(v) * (1.f / 64.f);
        float d   = v - mu;
        float var = wave_sum64(d * d) * (1.f / 64.f);
        float ov  = fmaf(d * rsqrtf(var + 1e-5f), g, be);
        if (do_relu) ov = fmaxf(ov, 0.f);
        h[pix * 64 + lane]   = ov;
        hbf[pix * 64 + lane] = f2bf(ov);
    }
}

// ---------------- head (MFMA): out = relu(hbf@q1W+q1b) . q2 + q2b ----------------
__global__ __launch_bounds__(256) void k_head_mfma(
    const unsigned short* __restrict__ hbf,   // [131072][64] bf16
    const unsigned short* __restrict__ q1bf,  // [128 j][64 k] bf16
    const float* __restrict__ q1b,            // [128]
    const float* __restrict__ q2,             // [128]
    const float* __restrict__ q2b,            // [1]
    float* __restrict__ out) {
    __shared__ unsigned short Q[8192];        // [j][k] swizzled
    int t = threadIdx.x;
    for (int c = t; c < 1024; c += 256) {
        int j = c >> 3, slot = c & 7;
        uint4 v = *(const uint4*)(q1bf + j * 64 + slot * 8);
        int byte = (j * 128 + slot * 16) ^ ((j & 7) << 4);
        *(uint4*)((char*)Q + byte) = v;
    }
    __syncthreads();

    int w = t >> 6, lane = t & 63;
    int lo = lane & 31, hi = lane >> 5;
    int px0 = blockIdx.x * 128 + w * 32;      // grid 1024

    bf16x8_t av[4];
    const unsigned short* hp = hbf + (size_t)(px0 + lo) * 64 + hi * 8;
#pragma unroll
    for (int ks = 0; ks < 4; ++ks)
        av[ks] = *(const bf16x8_t*)(hp + ks * 16);

    float res[16];
#pragma unroll
    for (int r = 0; r < 16; ++r) res[r] = 0.f;

#pragma unroll
    for (int jb = 0; jb < 4; ++jb) {
        f32x16_t acc = {};
        int j = jb * 32 + lo;
#pragma unroll
        for (int ks = 0; ks < 4; ++ks) {
            int byte = (j * 128 + ks * 32 + hi * 16) ^ ((j & 7) << 4);
            bf16x8_t bv = *(bf16x8_t*)((char*)Q + byte);
            acc = __builtin_amdgcn_mfma_f32_32x32x16_bf16(av[ks], bv, acc, 0, 0, 0);
        }
        float b1 = q1b[j];
        float w2 = q2[j];
#pragma unroll
        for (int r = 0; r < 16; ++r)
            res[r] = fmaf(fmaxf(acc[r] + b1, 0.f), w2, res[r]);
    }
#pragma unroll
    for (int r = 0; r < 16; ++r) {
        float v = res[r];
        v += __shfl_xor(v, 1);
        v += __shfl_xor(v, 2);
        v += __shfl_xor(v, 4);
        v += __shfl_xor(v, 8);
        v += __shfl_xor(v, 16);
        res[r] = v;
    }
    if (lo == 0) {
        float qb = q2b[0];
#pragma unroll
        for (int r = 0; r < 16; ++r) {
            int row = (r & 3) + 8 * (r >> 2) + 4 * hi;
            out[px0 + row] = res[r] + qb;
        }
    }
}

// ---------------- launch ----------------
extern "C" void kernel_launch(void* const* d_in, const int* in_sizes, int n_in,
                              void* d_out, int out_size, void* d_ws, size_t ws_size,
                              hipStream_t stream) {
    const float* x     = (const float*)d_in[0];
    const float* a     = (const float*)d_in[1];
    const float* pW    = (const float*)d_in[2];
    const float* pb    = (const float*)d_in[3];
    const float* q1W   = (const float*)d_in[4];
    const float* q1b   = (const float*)d_in[5];
    const float* q2W   = (const float*)d_in[6];
    const float* q2b   = (const float*)d_in[7];
    const float* phiW1 = (const float*)d_in[8];
    const float* phib1 = (const float*)d_in[9];
    const float* phiW2 = (const float*)d_in[10];
    const float* phib2 = (const float*)d_in[11];
    const float* phiW3 = (const float*)d_in[12];
    const float* phib3 = (const float*)d_in[13];
    const float* psiW1 = (const float*)d_in[14];
    const float* psib1 = (const float*)d_in[15];
    const float* psiW2 = (const float*)d_in[16];
    const float* psib2 = (const float*)d_in[17];
    const float* psiW3 = (const float*)d_in[18];
    const float* psib3 = (const float*)d_in[19];
    const float* lnG   = (const float*)d_in[20];
    const float* lnB   = (const float*)d_in[21];
    const float* convW = (const float*)d_in[22];
    const float* convb = (const float*)d_in[23];

    float* ws    = (float*)d_ws;
    float* h     = ws + OFF_H;
    float* x1    = ws + OFF_X1;
    float* yl1   = ws + OFF_YL1;
    float* yl2   = ws + OFF_YL2;
    unsigned short* hbf = (unsigned short*)(ws + OFF_HBF);
    float* H2psi = ws + OFF_H2PSI;
    float* x2c   = ws + OFF_H2PSI;            // overlay: H2psi dead after k_g
    float* H2phi = ws + OFF_H2PHI;
    unsigned short* cwtbf = (unsigned short*)(ws + OFF_CWTBF);
    unsigned short* q1bf  = (unsigned short*)(ws + OFF_Q1BF);
    float* G     = ws + OFF_G;
    float* sv    = ws + OFF_SV;
    float* C     = ws + OFF_C;
    float* D     = ws + OFF_D;

    k_transpose_convw_bf<<<1728, 256, 0, stream>>>(convW, cwtbf);
    k_transpose_q1bf<<<32, 256, 0, stream>>>(q1W, q1bf);

    k_lift<<<512, 256, 0, stream>>>(x, a, pW, pb, h, hbf);

    for (int i = 0; i < 4; ++i) {
        k_conv_mfma<<<672, 256, 0, stream>>>(hbf, cwtbf, convb, x1, yl1, yl2, i);

        k_mlp12<<<1024, 256, 0, stream>>>(a, x,
                                          psiW1 + i * 192, psib1 + i * 64,
                                          psiW2 + i * 8192, psib2 + i * 128,
                                          phiW1 + i * 192, phib1 + i * 64,
                                          phiW2 + i * 8192, phib2 + i * 128,
                                          H2psi, H2phi);
        hipMemsetAsync(G, 0, (16384 + 128) * sizeof(float), stream);  // G + sv
        k_g<<<128, 256, 0, stream>>>(h, H2psi, G, sv);
        k_yc<<<2, 256, 0, stream>>>(G, sv,
                                    psiW3 + (size_t)i * 32768, psib3 + i * 256,
                                    phiW3 + (size_t)i * 32768, phib3 + i * 256,
                                    C, D);
        k_x2c<<<128, 256, 0, stream>>>(H2phi, C, D, x2c);
        k_epilogue<<<8192, 256, 0, stream>>>(x1, yl1, yl2, x2c,
                                             lnG + i * 64, lnB + i * 64,
                                             h, hbf, (i < 3) ? 1 : 0);
    }

    k_head_mfma<<<1024, 256, 0, stream>>>(hbf, q1bf, q1b, q2W, q2b, (float*)d_out);
}

// Round 5
// 653.690 us; speedup vs baseline: 8.1798x; 1.2179x over previous
//
#include <hip/hip_runtime.h>
#include <cstddef>
#include <cstdint>

// ---------------- problem constants ----------------
// b=2, s=256, WIDTH=64, RANK=4, CLEVEL=1 (c=2), MLEVEL=2 (L=3), NB=4
// HID1=64, HID2=128

// ---------------- workspace layout (float offsets) ----------------
static constexpr size_t OFF_X1     = 0;          // 8388608
static constexpr size_t OFF_YL1    = 8388608;    // 2097152
static constexpr size_t OFF_YL2    = 10485760;   // 524288
static constexpr size_t OFF_HBF    = 11010048;   // bf16 NHWC h: 8388608 bf16 = 4194304 f32-slots
static constexpr size_t OFF_H2PSI  = 15204352;   // 4194304 (x2c overlays here after k_gpart)
static constexpr size_t OFF_H2PHI  = 19398656;   // 4194304
static constexpr size_t OFF_CWTBF  = 23592960;   // 221184
static constexpr size_t OFF_Q1BF   = 23814144;   // 4096
static constexpr size_t OFF_GPART  = 23818240;   // 512*8192 = 4194304
static constexpr size_t OFF_G      = 28012544;   // 16384
static constexpr size_t OFF_SV     = 28028928;   // 128
static constexpr size_t OFF_C      = 28029056;   // 16384
static constexpr size_t OFF_D      = 28045440;   // 128
// end = 28045568 floats (~112 MB) <= proven-available 134.3 MB

typedef __attribute__((ext_vector_type(8)))  short bf16x8_t;   // 8 bf16 in 4 VGPRs
typedef __attribute__((ext_vector_type(16))) float f32x16_t;   // 32x32 MFMA acc

// ---------------- helpers ----------------
__device__ inline float wave_sum64(float v) {
    v += __shfl_xor(v, 1);
    v += __shfl_xor(v, 2);
    v += __shfl_xor(v, 4);
    v += __shfl_xor(v, 8);
    v += __shfl_xor(v, 16);
    v += __shfl_xor(v, 32);
    return v;
}

__device__ inline unsigned short f2bf(float f) {   // round-to-nearest-even
    uint32_t u = __float_as_uint(f);
    uint32_t r = u + 0x7FFFu + ((u >> 16) & 1u);
    return (unsigned short)(r >> 16);
}

// full-res flat pixel index of coarse pixel (b, n): n in [0,16384)
__device__ inline size_t fullpix(int b, int n) {
    return (size_t)(b * 65536 + (n >> 7) * 512 + ((n & 127) << 1));
}

struct Lerp { int i0, i1; float f; };
__device__ inline Lerp lcoord(int o, float r, float off, int Sin) {
    float s = fmaxf(fmaf((float)o, r, off), 0.f);
    Lerp L;
    L.i0 = (int)s;
    L.f  = s - (float)L.i0;
    L.i1 = min(L.i0 + 1, Sin - 1);
    return L;
}
__device__ inline float bilerp64(const float* __restrict__ base, int Sin,
                                 const Lerp& ly, const Lerp& lx, int lane) {
    float v00 = base[((size_t)(ly.i0 * Sin + lx.i0)) * 64 + lane];
    float v01 = base[((size_t)(ly.i0 * Sin + lx.i1)) * 64 + lane];
    float v10 = base[((size_t)(ly.i1 * Sin + lx.i0)) * 64 + lane];
    float v11 = base[((size_t)(ly.i1 * Sin + lx.i1)) * 64 + lane];
    float a = v00 + lx.f * (v01 - v00);
    float b = v10 + lx.f * (v11 - v10);
    return a + ly.f * (b - a);
}

// ---------------- weight transforms ----------------
// convW[i][l][oc][ic][3][3] f32 -> cwtbf[i*3+l][oc][tap*64+ic] bf16
__global__ __launch_bounds__(256) void k_transpose_convw_bf(const float* __restrict__ w,
                                                            unsigned short* __restrict__ wt) {
    int idx = blockIdx.x * 256 + threadIdx.x;     // 12*64*576 = 442368
    if (idx >= 442368) return;
    int k    = idx % 576;
    int rest = idx / 576;
    int oc   = rest & 63;
    int il   = rest >> 6;
    int tap  = k >> 6;
    int ic   = k & 63;
    wt[idx] = f2bf(w[((size_t)(il * 64 + oc) * 64 + ic) * 9 + tap]);
}
// q1W[64][128] f32 -> q1bf[j][k] bf16 (transposed)
__global__ __launch_bounds__(256) void k_transpose_q1bf(const float* __restrict__ w,
                                                        unsigned short* __restrict__ wt) {
    int idx = blockIdx.x * 256 + threadIdx.x;     // 8192
    if (idx >= 8192) return;
    int k = idx & 63;
    int j = idx >> 6;
    wt[j * 64 + k] = f2bf(w[k * 128 + j]);
}

// ---------------- lift: h = [a0,a1,x] @ pW + pb (writes bf16 NHWC) ----------------
__global__ __launch_bounds__(256) void k_lift(const float* __restrict__ x,
                                              const float* __restrict__ a,
                                              const float* __restrict__ pW,
                                              const float* __restrict__ pb,
                                              unsigned short* __restrict__ hbf) {
    int p = blockIdx.x * 256 + threadIdx.x;       // 131072
    float a0 = a[(size_t)p * 2 + 0];
    float a1 = a[(size_t)p * 2 + 1];
    float xv = x[p];
    float vals[64];
#pragma unroll
    for (int c = 0; c < 64; ++c)
        vals[c] = fmaf(a0, pW[c], fmaf(a1, pW[64 + c], fmaf(xv, pW[128 + c], pb[c])));
    unsigned short us[64];
#pragma unroll
    for (int c = 0; c < 64; ++c) us[c] = f2bf(vals[c]);
    unsigned short* bp = hbf + (size_t)p * 64;
#pragma unroll
    for (int c = 0; c < 64; c += 8)
        *(uint4*)(bp + c) = *(uint4*)(us + c);
}

// ---------------- MFMA conv 3x3 SAME (64->64), all 3 levels in one grid ----------------
__global__ __launch_bounds__(256) void k_conv_mfma(
    const unsigned short* __restrict__ hbf,   // [2][256][256][64] bf16
    const unsigned short* __restrict__ wbf,   // [12][64][576] bf16
    const float* __restrict__ convb,          // [12][64]
    float* __restrict__ x1, float* __restrict__ yl1, float* __restrict__ yl2,
    int iter) {
    __shared__ unsigned short Ald[20736];     // 324 px * 64 ic  (41472 B)
    __shared__ unsigned short Bld[36864];     // 64 oc * 576 k   (73728 B)

    int bid = blockIdx.x;
    int lvl, tix, Sl, st, tpr;
    if (bid < 512)      { lvl = 0; tix = bid;       Sl = 256; st = 1; tpr = 16; }
    else if (bid < 640) { lvl = 1; tix = bid - 512; Sl = 128; st = 2; tpr = 8;  }
    else                { lvl = 2; tix = bid - 640; Sl = 64;  st = 4; tpr = 4;  }
    int tpb = tpr * tpr;
    int b = tix / tpb;
    int r = tix - b * tpb;
    int y0 = (r / tpr) * 16, x0 = (r % tpr) * 16;
    int t = threadIdx.x;

    // ---- stage A: 18x18 halo x 64 ic, zero-padded at image edges ----
    for (int c = t; c < 2592; c += 256) {       // 2592 = 324 rows * 8 slots(16B)
        int lin = c >> 3, slot = c & 7;
        int ty = lin / 18, tx = lin - ty * 18;
        int oy = y0 + ty - 1, ox = x0 + tx - 1;
        uint4 val = make_uint4(0u, 0u, 0u, 0u);
        if ((unsigned)oy < (unsigned)Sl && (unsigned)ox < (unsigned)Sl) {
            const unsigned short* src =
                hbf + (((size_t)(b * 256 + oy * st) * 256 + ox * st) << 6) + (slot << 3);
            val = *(const uint4*)src;
        }
        int byte = (lin << 7) + (((slot ^ (lin & 7))) << 4);
        *(uint4*)((char*)Ald + byte) = val;
    }
    // ---- stage B: weights for this (iter,lvl) ----
    {
        const unsigned short* wsrc = wbf + (size_t)(iter * 3 + lvl) * 36864;
        int oc = t >> 2, q = t & 3;
#pragma unroll
        for (int j = 0; j < 18; ++j) {
            int koff = q * 144 + j * 8;                 // bf16 elems
            uint4 v = *(const uint4*)(wsrc + oc * 576 + koff);
            int byte = (oc * 1152 + (koff << 1)) ^ ((oc & 7) << 4);
            *(uint4*)((char*)Bld + byte) = v;
        }
    }
    __syncthreads();

    // ---- compute ----
    int w    = t >> 6;
    int lane = t & 63;
    int lo   = lane & 31;
    int hi   = lane >> 5;
    f32x16_t acc00 = {}, acc01 = {}, acc10 = {}, acc11 = {};

    int yA0 = 4 * w + (lo >> 4);
    int xA  = lo & 15;
#pragma unroll 3
    for (int tap = 0; tap < 9; ++tap) {
        int dy = tap / 3, dx = tap - dy * 3;
        int lin0 = (yA0 + dy) * 18 + (xA + dx);
        int lin1 = lin0 + 36;
#pragma unroll
        for (int kq = 0; kq < 4; ++kq) {
            int icb = (kq << 5) + (hi << 4);
            int a0b = ((lin0 << 7) + icb) ^ ((lin0 & 7) << 4);
            int a1b = ((lin1 << 7) + icb) ^ ((lin1 & 7) << 4);
            bf16x8_t va0 = *(bf16x8_t*)((char*)Ald + a0b);
            bf16x8_t va1 = *(bf16x8_t*)((char*)Ald + a1b);
            int kk  = tap * 128 + icb;
            int b0b = (lo * 1152 + kk) ^ ((lo & 7) << 4);
            int b1b = ((lo + 32) * 1152 + kk) ^ ((lo & 7) << 4);
            bf16x8_t vb0 = *(bf16x8_t*)((char*)Bld + b0b);
            bf16x8_t vb1 = *(bf16x8_t*)((char*)Bld + b1b);
            acc00 = __builtin_amdgcn_mfma_f32_32x32x16_bf16(va0, vb0, acc00, 0, 0, 0);
            acc01 = __builtin_amdgcn_mfma_f32_32x32x16_bf16(va0, vb1, acc01, 0, 0, 0);
            acc10 = __builtin_amdgcn_mfma_f32_32x32x16_bf16(va1, vb0, acc10, 0, 0, 0);
            acc11 = __builtin_amdgcn_mfma_f32_32x32x16_bf16(va1, vb1, acc11, 0, 0, 0);
        }
    }

    // ---- store ----
    float* out = (lvl == 0) ? x1 : (lvl == 1 ? yl1 : yl2);
    const float* bias = convb + (iter * 3 + lvl) * 64;
    float bias0 = bias[lo];
    float bias1 = bias[32 + lo];
#pragma unroll
    for (int reg = 0; reg < 16; ++reg) {
        int row = (reg & 3) + 8 * (reg >> 2) + 4 * hi;
        int yt  = 4 * w + (row >> 4);
        int xt  = row & 15;
        size_t pix0 = ((size_t)(b * Sl + y0 + yt) * Sl + (x0 + xt)) << 6;
        out[pix0 + lo]      = acc00[reg] + bias0;
        out[pix0 + 32 + lo] = acc01[reg] + bias1;
        size_t pix1 = ((size_t)(b * Sl + y0 + yt + 2) * Sl + (x0 + xt)) << 6;
        out[pix1 + lo]      = acc10[reg] + bias0;
        out[pix1 + 32 + lo] = acc11[reg] + bias1;
    }
}

// ---------------- mlp12: H2 = relu(relu(a@W1+b1)@W2+b2), 4 threads/px ----------------
__global__ __launch_bounds__(256) void k_mlp12(
    const float* __restrict__ a, const float* __restrict__ x,
    const float* __restrict__ W1a, const float* __restrict__ b1a,
    const float* __restrict__ W2a, const float* __restrict__ b2a,
    const float* __restrict__ W1b, const float* __restrict__ b1b,
    const float* __restrict__ W2b, const float* __restrict__ b2b,
    float* __restrict__ H2a, float* __restrict__ H2b) {
    int blk = blockIdx.x;                          // 1024
    int m = blk >> 9;
    int t = threadIdx.x;
    int pxl = ((blk & 511) << 6) | (t & 63);       // 0..32767
    int j0 = __builtin_amdgcn_readfirstlane((t >> 6) << 5);  // 0/32/64/96
    const float* W1 = m ? W1b : W1a;
    const float* b1 = m ? b1b : b1a;
    const float* W2 = m ? W2b : W2a;
    const float* b2 = m ? b2b : b2a;
    float* H2 = m ? H2b : H2a;
    int b = pxl >> 14, n = pxl & 16383;
    size_t apix = fullpix(b, n);
    float a0 = a[apix * 2], a1 = a[apix * 2 + 1], xv = x[apix];

    float acc[32];
#pragma unroll
    for (int j = 0; j < 32; ++j) acc[j] = b2[j0 + j];
#pragma unroll 1
    for (int k = 0; k < 64; ++k) {
        float h1 = fmaxf(fmaf(a0, W1[k], fmaf(a1, W1[64 + k], fmaf(xv, W1[128 + k], b1[k]))), 0.f);
        const float* wr = W2 + k * 128 + j0;
#pragma unroll
        for (int j = 0; j < 32; ++j) acc[j] = fmaf(h1, wr[j], acc[j]);
    }
    float* op = H2 + (size_t)pxl * 128 + j0;
#pragma unroll
    for (int j = 0; j < 32; j += 4)
        *(float4*)(op + j) = make_float4(fmaxf(acc[j], 0.f), fmaxf(acc[j + 1], 0.f),
                                         fmaxf(acc[j + 2], 0.f), fmaxf(acc[j + 3], 0.f));
}

// ---------------- split-K stage 1: Gpart[blk][w][k] = sum_{64px} v*H2; sv atomic ----------------
__global__ __launch_bounds__(256) void k_gpart(const unsigned short* __restrict__ hbf,
                                               const float* __restrict__ H2psi,
                                               float* __restrict__ Gpart,
                                               float* __restrict__ sv) {
    __shared__ float vt[64][64];
    __shared__ float h2t[64][128];
    int blk = blockIdx.x;            // 512
    int b = blk >> 8;
    int n0 = (blk & 255) << 6;       // 64 px per block
    int t = threadIdx.x;
    int pxq = t >> 2;                // 0..63
    int qq  = t & 3;
    {
        int n = n0 + pxq;
        const unsigned short* src = hbf + fullpix(b, n) * 64 + qq * 16;
        uint4 u0 = *(const uint4*)src;
        uint4 u1 = *(const uint4*)(src + 8);
        unsigned uv[8] = {u0.x, u0.y, u0.z, u0.w, u1.x, u1.y, u1.z, u1.w};
        float* dst = &vt[pxq][qq * 16];
#pragma unroll
        for (int i = 0; i < 8; ++i) {
            dst[2 * i]     = __uint_as_float((uv[i] & 0xFFFFu) << 16);
            dst[2 * i + 1] = __uint_as_float(uv[i] & 0xFFFF0000u);
        }
        const float* hsrc = &H2psi[((size_t)(b * 16384 + n)) * 128 + qq * 32];
        float* hdst = &h2t[pxq][qq * 32];
#pragma unroll
        for (int rr = 0; rr < 8; ++rr)
            *(float4*)(hdst + rr * 4) = *(const float4*)(hsrc + rr * 4);
    }
    __syncthreads();

    int wt_ = (t >> 5) << 3;         // 0..56
    int kt  = (t & 31) << 2;         // 0..124
    float acc[8][4];
#pragma unroll
    for (int i = 0; i < 8; ++i)
#pragma unroll
        for (int j = 0; j < 4; ++j) acc[i][j] = 0.f;

#pragma unroll 4
    for (int nn = 0; nn < 64; ++nn) {
        float4 hv = *(float4*)&h2t[nn][kt];
        float4 v0 = *(float4*)&vt[nn][wt_];
        float4 v1 = *(float4*)&vt[nn][wt_ + 4];
        float vv[8] = {v0.x, v0.y, v0.z, v0.w, v1.x, v1.y, v1.z, v1.w};
        float hh[4] = {hv.x, hv.y, hv.z, hv.w};
#pragma unroll
        for (int i = 0; i < 8; ++i)
#pragma unroll
            for (int j = 0; j < 4; ++j) acc[i][j] = fmaf(vv[i], hh[j], acc[i][j]);
    }

    float* gp = Gpart + (size_t)blk * 8192;
#pragma unroll
    for (int i = 0; i < 8; ++i)
        *(float4*)&gp[(wt_ + i) * 128 + kt] =
            make_float4(acc[i][0], acc[i][1], acc[i][2], acc[i][3]);

    // sv: column sums of vt
    if (t < 64) {
        float s = 0.f;
#pragma unroll 8
        for (int px = 0; px < 64; ++px) s += vt[px][t];
        atomicAdd(&sv[b * 64 + t], s);
    }
}

// ---------------- split-K stage 2: G = sum over 256 chunks of Gpart ----------------
__global__ __launch_bounds__(256) void k_gred(const float* __restrict__ Gpart,
                                              float* __restrict__ G) {
    __shared__ float red[4][64];
    int blk = blockIdx.x;            // 256
    int b  = blk >> 7;
    int es = (blk & 127) << 6;       // 64 outputs per block
    int t = threadIdx.x;
    int e  = es + (t & 63);
    int cg = t >> 6;                 // 4 chunk-groups
    float s = 0.f;
    const float* gp = Gpart + ((size_t)(b * 256 + cg * 64)) * 8192 + e;
#pragma unroll 8
    for (int c = 0; c < 64; ++c) s += gp[(size_t)c * 8192];
    red[cg][t & 63] = s;
    __syncthreads();
    if (t < 64)
        G[b * 8192 + es + t] = red[0][t] + red[1][t] + red[2][t] + red[3][t];
}

// ---------------- finalize: ybar -> c[b][w][k], d[b][w] (grid 32) ----------------
__global__ __launch_bounds__(256) void k_yc(const float* __restrict__ G,
                                            const float* __restrict__ sv,
                                            const float* __restrict__ W3psi,
                                            const float* __restrict__ b3psi,
                                            const float* __restrict__ W3phi,
                                            const float* __restrict__ b3phi,
                                            float* __restrict__ C,
                                            float* __restrict__ D) {
    __shared__ float ybar[256];
    int bq = blockIdx.x;             // 32
    int b = bq >> 4, q = bq & 15;
    int t = threadIdx.x;
    {
        int o = t, w = o >> 2;
        float s = b3psi[o] * sv[b * 64 + w];
        const float* gp = &G[(size_t)(b * 64 + w) * 128];
#pragma unroll 4
        for (int k = 0; k < 128; ++k) s = fmaf(W3psi[k * 256 + o], gp[k], s);
        ybar[o] = s * (1.f / 16384.f);
    }
    __syncthreads();
#pragma unroll
    for (int rep = 0; rep < 2; ++rep) {
        int e = q * 512 + rep * 256 + t;   // this block's slice of 8192
        int w = e >> 7, k = e & 127;
        const float* wp = &W3phi[k * 256 + w * 4];
        C[b * 8192 + e] = fmaf(wp[0], ybar[w * 4],
                          fmaf(wp[1], ybar[w * 4 + 1],
                          fmaf(wp[2], ybar[w * 4 + 2], wp[3] * ybar[w * 4 + 3])));
    }
    if (q == 0 && t < 64) {
        int w = t;
        D[b * 64 + w] = b3phi[w * 4] * ybar[w * 4] + b3phi[w * 4 + 1] * ybar[w * 4 + 1]
                      + b3phi[w * 4 + 2] * ybar[w * 4 + 2] + b3phi[w * 4 + 3] * ybar[w * 4 + 3];
    }
}

// ---------------- x2c[px][w] = H2phi[px][:] . c[b][w][:] + d[b][w] ----------------
__global__ __launch_bounds__(256) void k_x2c(const float* __restrict__ H2phi,
                                             const float* __restrict__ C,
                                             const float* __restrict__ D,
                                             float* __restrict__ x2c) {
    __shared__ float cl[8192];
    int blk = blockIdx.x;            // 128
    int b = blk >> 6;
    int px0 = blk << 8;
    int t = threadIdx.x;
    const float* cp = C + b * 8192;
#pragma unroll
    for (int rep = 0; rep < 8; ++rep) {
        int f = rep * 1024 + t * 4;
        *(float4*)&cl[f] = *(const float4*)&cp[f];
    }
    __syncthreads();

    int w0 = __builtin_amdgcn_readfirstlane((t >> 6) << 4);
    int px = px0 + ((t & 63) << 2);
    float acc[4][16];
#pragma unroll
    for (int i = 0; i < 4; ++i)
#pragma unroll
        for (int j = 0; j < 16; ++j) acc[i][j] = 0.f;

    const float* hbase = H2phi + (size_t)px * 128;
#pragma unroll 2
    for (int kq = 0; kq < 32; ++kq) {
        float4 h2q[4];
#pragma unroll
        for (int i = 0; i < 4; ++i) h2q[i] = *(const float4*)&hbase[i * 128 + kq * 4];
#pragma unroll
        for (int j = 0; j < 16; ++j) {
            float4 cq = *(float4*)&cl[(w0 + j) * 128 + kq * 4];
#pragma unroll
            for (int i = 0; i < 4; ++i) {
                acc[i][j] = fmaf(h2q[i].x, cq.x, acc[i][j]);
                acc[i][j] = fmaf(h2q[i].y, cq.y, acc[i][j]);
                acc[i][j] = fmaf(h2q[i].z, cq.z, acc[i][j]);
                acc[i][j] = fmaf(h2q[i].w, cq.w, acc[i][j]);
            }
        }
    }
#pragma unroll
    for (int i = 0; i < 4; ++i) {
        float* op = &x2c[(size_t)(px + i) * 64 + w0];
#pragma unroll
        for (int j = 0; j < 16; j += 4) {
            float4 o4 = make_float4(acc[i][j]     + D[b * 64 + w0 + j],
                                    acc[i][j + 1] + D[b * 64 + w0 + j + 1],
                                    acc[i][j + 2] + D[b * 64 + w0 + j + 2],
                                    acc[i][j + 3] + D[b * 64 + w0 + j + 3]);
            *(float4*)(op + j) = o4;
        }
    }
}

// ---------------- epilogue: h = LN(x1 + up(yl1) + up(yl2) + up(x2c)); writes bf16 ----------------
__global__ __launch_bounds__(256) void k_epilogue(const float* __restrict__ x1,
                                                  const float* __restrict__ yl1,
                                                  const float* __restrict__ yl2,
                                                  const float* __restrict__ x2c,
                                                  const float* __restrict__ lnG,
                                                  const float* __restrict__ lnB,
                                                  unsigned short* __restrict__ hbf,
                                                  int do_relu) {
    int t    = threadIdx.x;
    int blk  = blockIdx.x;                 // 8192 = 2 * 256 * 16
    int b    = blk >> 12;
    int rest = blk & 4095;
    int y    = rest >> 4;
    int x0   = (rest & 15) << 4;
    int wv = t >> 6, lane = t & 63;

    float g = lnG[lane], be = lnB[lane];
    const float* Y1 = yl1 + (size_t)b * 16384 * 64;
    const float* Y2 = yl2 + (size_t)b * 4096 * 64;
    const float* XC = x2c + (size_t)b * 16384 * 64;

    for (int pp = 0; pp < 4; ++pp) {
        int xx = x0 + wv * 4 + pp;
        size_t pix = (size_t)((b * 256 + y) * 256 + xx);
        float v = x1[pix * 64 + lane];
        {
            Lerp ly = lcoord(y, 0.5f, -0.25f, 128);
            Lerp lx = lcoord(xx, 0.5f, -0.25f, 128);
            v += bilerp64(Y1, 128, ly, lx, lane);
        }
        {
            Lerp ly = lcoord(y, 0.25f, -0.375f, 64);
            Lerp lx = lcoord(xx, 0.25f, -0.375f, 64);
            v += bilerp64(Y2, 64, ly, lx, lane);
        }
        {
            Lerp ly = lcoord(y, 0.5f, -0.25f, 128);
            Lerp lx = lcoord(xx, 0.5f, -0.25f, 128);
            v += bilerp64(XC, 128, ly, lx, lane);
        }
        float mu  = wave_sum64(v) * (1.f / 64.f);
        float d   = v - mu;
        float var = wave_sum64(d * d) * (1.f / 64.f);
        float ov  = fmaf(d * rsqrtf(var + 1e-5f), g, be);
        if (do_relu) ov = fmaxf(ov, 0.f);
        hbf[pix * 64 + lane] = f2bf(ov);
    }
}

// ---------------- head (MFMA): out = relu(hbf@q1W+q1b) . q2 + q2b ----------------
__global__ __launch_bounds__(256) void k_head_mfma(
    const unsigned short* __restrict__ hbf,   // [131072][64] bf16
    const unsigned short* __restrict__ q1bf,  // [128 j][64 k] bf16
    const float* __restrict__ q1b,            // [128]
    const float* __restrict__ q2,             // [128]
    const float* __restrict__ q2b,            // [1]
    float* __restrict__ out) {
    __shared__ unsigned short Q[8192];        // [j][k] swizzled
    int t = threadIdx.x;
    for (int c = t; c < 1024; c += 256) {
        int j = c >> 3, slot = c & 7;
        uint4 v = *(const uint4*)(q1bf + j * 64 + slot * 8);
        int byte = (j * 128 + slot * 16) ^ ((j & 7) << 4);
        *(uint4*)((char*)Q + byte) = v;
    }
    __syncthreads();

    int w = t >> 6, lane = t & 63;
    int lo = lane & 31, hi = lane >> 5;
    int px0 = blockIdx.x * 128 + w * 32;      // grid 1024

    bf16x8_t av[4];
    const unsigned short* hp = hbf + (size_t)(px0 + lo) * 64 + hi * 8;
#pragma unroll
    for (int ks = 0; ks < 4; ++ks)
        av[ks] = *(const bf16x8_t*)(hp + ks * 16);

    float res[16];
#pragma unroll
    for (int r = 0; r < 16; ++r) res[r] = 0.f;

#pragma unroll
    for (int jb = 0; jb < 4; ++jb) {
        f32x16_t acc = {};
        int j = jb * 32 + lo;
#pragma unroll
        for (int ks = 0; ks < 4; ++ks) {
            int byte = (j * 128 + ks * 32 + hi * 16) ^ ((j & 7) << 4);
            bf16x8_t bv = *(bf16x8_t*)((char*)Q + byte);
            acc = __builtin_amdgcn_mfma_f32_32x32x16_bf16(av[ks], bv, acc, 0, 0, 0);
        }
        float b1 = q1b[j];
        float w2 = q2[j];
#pragma unroll
        for (int r = 0; r < 16; ++r)
            res[r] = fmaf(fmaxf(acc[r] + b1, 0.f), w2, res[r]);
    }
#pragma unroll
    for (int r = 0; r < 16; ++r) {
        float v = res[r];
        v += __shfl_xor(v, 1);
        v += __shfl_xor(v, 2);
        v += __shfl_xor(v, 4);
        v += __shfl_xor(v, 8);
        v += __shfl_xor(v, 16);
        res[r] = v;
    }
    if (lo == 0) {
        float qb = q2b[0];
#pragma unroll
        for (int r = 0; r < 16; ++r) {
            int row = (r & 3) + 8 * (r >> 2) + 4 * hi;
            out[px0 + row] = res[r] + qb;
        }
    }
}

// ---------------- launch ----------------
extern "C" void kernel_launch(void* const* d_in, const int* in_sizes, int n_in,
                              void* d_out, int out_size, void* d_ws, size_t ws_size,
                              hipStream_t stream) {
    const float* x     = (const float*)d_in[0];
    const float* a     = (const float*)d_in[1];
    const float* pW    = (const float*)d_in[2];
    const float* pb    = (const float*)d_in[3];
    const float* q1W   = (const float*)d_in[4];
    const float* q1b   = (const float*)d_in[5];
    const float* q2W   = (const float*)d_in[6];
    const float* q2b   = (const float*)d_in[7];
    const float* phiW1 = (const float*)d_in[8];
    const float* phib1 = (const float*)d_in[9];
    const float* phiW2 = (const float*)d_in[10];
    const float* phib2 = (const float*)d_in[11];
    const float* phiW3 = (const float*)d_in[12];
    const float* phib3 = (const float*)d_in[13];
    const float* psiW1 = (const float*)d_in[14];
    const float* psib1 = (const float*)d_in[15];
    const float* psiW2 = (const float*)d_in[16];
    const float* psib2 = (const float*)d_in[17];
    const float* psiW3 = (const float*)d_in[18];
    const float* psib3 = (const float*)d_in[19];
    const float* lnG   = (const float*)d_in[20];
    const float* lnB   = (const float*)d_in[21];
    const float* convW = (const float*)d_in[22];
    const float* convb = (const float*)d_in[23];

    float* ws    = (float*)d_ws;
    float* x1    = ws + OFF_X1;
    float* yl1   = ws + OFF_YL1;
    float* yl2   = ws + OFF_YL2;
    unsigned short* hbf = (unsigned short*)(ws + OFF_HBF);
    float* H2psi = ws + OFF_H2PSI;
    float* x2c   = ws + OFF_H2PSI;            // overlay: H2psi dead after k_gpart
    float* H2phi = ws + OFF_H2PHI;
    unsigned short* cwtbf = (unsigned short*)(ws + OFF_CWTBF);
    unsigned short* q1bf  = (unsigned short*)(ws + OFF_Q1BF);
    float* Gpart = ws + OFF_GPART;
    float* G     = ws + OFF_G;
    float* sv    = ws + OFF_SV;
    float* C     = ws + OFF_C;
    float* D     = ws + OFF_D;

    k_transpose_convw_bf<<<1728, 256, 0, stream>>>(convW, cwtbf);
    k_transpose_q1bf<<<32, 256, 0, stream>>>(q1W, q1bf);

    k_lift<<<512, 256, 0, stream>>>(x, a, pW, pb, hbf);

    for (int i = 0; i < 4; ++i) {
        k_conv_mfma<<<672, 256, 0, stream>>>(hbf, cwtbf, convb, x1, yl1, yl2, i);

        k_mlp12<<<1024, 256, 0, stream>>>(a, x,
                                          psiW1 + i * 192, psib1 + i * 64,
                                          psiW2 + i * 8192, psib2 + i * 128,
                                          phiW1 + i * 192, phib1 + i * 64,
                                          phiW2 + i * 8192, phib2 + i * 128,
                                          H2psi, H2phi);
        hipMemsetAsync(sv, 0, 128 * sizeof(float), stream);
        k_gpart<<<512, 256, 0, stream>>>(hbf, H2psi, Gpart, sv);
        k_gred<<<256, 256, 0, stream>>>(Gpart, G);
        k_yc<<<32, 256, 0, stream>>>(G, sv,
                                     psiW3 + (size_t)i * 32768, psib3 + i * 256,
                                     phiW3 + (size_t)i * 32768, phib3 + i * 256,
                                     C, D);
        k_x2c<<<128, 256, 0, stream>>>(H2phi, C, D, x2c);
        k_epilogue<<<8192, 256, 0, stream>>>(x1, yl1, yl2, x2c,
                                             lnG + i * 64, lnB + i * 64,
                                             hbf, (i < 3) ? 1 : 0);
    }

    k_head_mfma<<<1024, 256, 0, stream>>>(hbf, q1bf, q1b, q2W, q2b, (float*)d_out);
}